// Round 3
// baseline (1289.722 us; speedup 1.0000x reference)
//
#include <hip/hip_runtime.h>
#include <math.h>

#define BJ 192
#define L 512
#define D 128
#define ROWS (BJ*L)          // 98304
#define TI 128
#define TJ 64

#define COMP(v,i) ((i)==0?(v).x:((i)==1?(v).y:((i)==2?(v).z:(v).w)))

typedef __bf16 bf16x8 __attribute__((ext_vector_type(8)));
typedef float  f32x4  __attribute__((ext_vector_type(4)));

__device__ __forceinline__ unsigned short f2bf(float f) {
    unsigned int u = __float_as_uint(f);
    unsigned int r = (u + 0x7fffu + ((u >> 16) & 1u)) >> 16;   // RNE
    return (unsigned short)r;
}

// ---------------- K1: xn = x / max(norm(x),1e-12) (np-bit-exact) + bf16 copy ----------------
__global__ __launch_bounds__(256) void k_normalize(const float* __restrict__ x,
                                                   float* __restrict__ xn,
                                                   unsigned short* __restrict__ xnbf) {
    __shared__ float s_x[64 * 132];
    __shared__ float s_nrm[64];
    int t = threadIdx.x;
    size_t row0 = (size_t)blockIdx.x * 64;

    #pragma unroll
    for (int r = 0; r < 8; ++r) {
        int id = t + 256 * r;
        int row = id >> 5, c4 = (id & 31) << 2;
        *(float4*)&s_x[row * 132 + c4] = *(const float4*)(x + (row0 + row) * D + c4);
    }
    __syncthreads();
    if (t < 64) {
        int row = t;
        const float* p = &s_x[row * 132];
        float r8[8];
        #pragma unroll
        for (int l = 0; l < 8; ++l) r8[l] = 0.0f;
        #pragma unroll 1
        for (int i = 0; i < 16; ++i) {
            #pragma unroll
            for (int l = 0; l < 8; ++l) {
                float v = p[i * 8 + l];
                r8[l] = __fadd_rn(r8[l], __fmul_rn(v, v));
            }
        }
        float s01 = __fadd_rn(r8[0], r8[1]);
        float s23 = __fadd_rn(r8[2], r8[3]);
        float s45 = __fadd_rn(r8[4], r8[5]);
        float s67 = __fadd_rn(r8[6], r8[7]);
        float ss  = __fadd_rn(__fadd_rn(s01, s23), __fadd_rn(s45, s67));
        s_nrm[row] = fmaxf(__fsqrt_rn(ss), 1e-12f);
    }
    __syncthreads();
    {
        int row = t >> 2, seg = t & 3;
        float nrm = s_nrm[row];
        float* outp = xn + (row0 + row) * D + seg * 32;
        unsigned short* outb = xnbf + (row0 + row) * D + seg * 32;
        #pragma unroll
        for (int c = 0; c < 8; ++c) {
            float4 v = *(const float4*)&s_x[row * 132 + seg * 32 + c * 4];
            float4 o;
            o.x = __fdiv_rn(v.x, nrm);
            o.y = __fdiv_rn(v.y, nrm);
            o.z = __fdiv_rn(v.z, nrm);
            o.w = __fdiv_rn(v.w, nrm);
            *(float4*)(outp + c * 4) = o;
            ushort4 ob;
            ob.x = f2bf(o.x); ob.y = f2bf(o.y); ob.z = f2bf(o.z); ob.w = f2bf(o.w);
            *(ushort4*)(outb + c * 4) = ob;
        }
    }
}

// ---------------- K2a: bf16-MFMA candidate scores -> 32 candidate indices per row ------------
__global__ __launch_bounds__(256, 3) void k_topk_cand(const unsigned short* __restrict__ xnbf,
                                                      unsigned short* __restrict__ cand) {
    __shared__ __align__(16) char smem[34816];
    float* s_sc = (float*)smem;            // 128*68 floats, aliased over Xi/Bj staging

    int bj = blockIdx.y;
    int i0 = blockIdx.x * TI;
    int t  = threadIdx.x;
    int w  = t >> 6;            // wave 0..3
    int l  = t & 63;            // lane
    int quad = l >> 4;          // 0..3
    int m16  = l & 15;          // 0..15
    const unsigned short* xfb = xnbf + (size_t)bj * L * D;

    // ---- stage Xi (bf16, swizzled) ----
    #pragma unroll
    for (int r = 0; r < 8; ++r) {
        int id = t + 256 * r;
        int row = id >> 4, c = id & 15;
        uint4 v = *(const uint4*)(xfb + (size_t)(i0 + row) * D + c * 8);
        *(uint4*)(smem + row * 256 + ((c ^ (row & 15)) << 4)) = v;
    }
    __syncthreads();
    bf16x8 afr[2][4];
    #pragma unroll
    for (int mt = 0; mt < 2; ++mt)
        #pragma unroll
        for (int s = 0; s < 4; ++s) {
            int row = w * 32 + mt * 16 + m16;
            int c = s * 4 + quad;
            afr[mt][s] = *(const bf16x8*)(smem + row * 256 + ((c ^ m16) << 4));
        }
    __syncthreads();   // Xi region free

    float tv[16]; int tjx[16];
    #pragma unroll
    for (int c = 0; c < 16; ++c) { tv[c] = -3.4e38f; tjx[c] = 0; }

    for (int jt = 0; jt < L / TJ; ++jt) {   // 8 j-tiles of 64
        #pragma unroll
        for (int r = 0; r < 4; ++r) {
            int id = t + 256 * r;
            int row = id >> 4, c = id & 15;
            uint4 v = *(const uint4*)(xfb + (size_t)(jt * TJ + row) * D + c * 8);
            *(uint4*)(smem + row * 256 + ((c ^ (row & 15)) << 4)) = v;
        }
        __syncthreads();
        f32x4 acc[2][4];
        #pragma unroll
        for (int mt = 0; mt < 2; ++mt)
            #pragma unroll
            for (int u = 0; u < 4; ++u) acc[mt][u] = (f32x4){0.f, 0.f, 0.f, 0.f};
        #pragma unroll
        for (int s = 0; s < 4; ++s) {
            bf16x8 bfr[4];
            #pragma unroll
            for (int u = 0; u < 4; ++u) {
                int row = u * 16 + m16;
                int c = s * 4 + quad;
                bfr[u] = *(const bf16x8*)(smem + row * 256 + ((c ^ m16) << 4));
            }
            #pragma unroll
            for (int u = 0; u < 4; ++u)
                #pragma unroll
                for (int mt = 0; mt < 2; ++mt)
                    acc[mt][u] = __builtin_amdgcn_mfma_f32_16x16x32_bf16(
                        afr[mt][s], bfr[u], acc[mt][u], 0, 0, 0);
        }
        __syncthreads();   // Bj consumed; region now s_sc
        // C/D layout: col = lane&15, row = quad*4 + reg  [m89-verified]
        #pragma unroll
        for (int mt = 0; mt < 2; ++mt)
            #pragma unroll
            for (int u = 0; u < 4; ++u)
                #pragma unroll
                for (int reg = 0; reg < 4; ++reg) {
                    int irow = w * 32 + mt * 16 + quad * 4 + reg;
                    s_sc[irow * 68 + u * 16 + m16] = acc[mt][u][reg];
                }
        __syncthreads();
        // scan (pool semantics identical to R7: strict >, earlier j kept on ties)
        {
            int row = t & 127, q = t >> 7;
            const float* bp = &s_sc[row * 68 + q * 32];
            int jbase = jt * TJ + q * 32;
            float4 cur = *(const float4*)bp;
            #pragma unroll 1
            for (int s4 = 0; s4 < 8; ++s4) {
                float4 nxt = cur;
                if (s4 < 7) nxt = *(const float4*)(bp + (s4 + 1) * 4);
                float mx = fmaxf(fmaxf(cur.x, cur.y), fmaxf(cur.z, cur.w));
                if (mx > tv[15]) {
                    #pragma unroll
                    for (int e = 0; e < 4; ++e) {
                        float v = COMP(cur, e);
                        if (v > tv[15]) {
                            tv[15] = v; tjx[15] = jbase + s4 * 4 + e;
                            #pragma unroll
                            for (int p = 15; p > 0; --p) {
                                if (tv[p] > tv[p - 1]) {
                                    float ft = tv[p - 1]; tv[p - 1] = tv[p]; tv[p] = ft;
                                    int   it = tjx[p - 1]; tjx[p - 1] = tjx[p]; tjx[p] = it;
                                }
                            }
                        }
                    }
                }
                cur = nxt;
            }
        }
        __syncthreads();   // scan done before next stage overwrites
    }

    // dump candidates: row-global layout [R*32 + q*16 + c], j fits u16
    {
        int rowB = t & 127, qB = t >> 7;
        unsigned short* cp = cand + ((size_t)(bj * L + i0 + rowB)) * 32 + qB * 16;
        #pragma unroll
        for (int c = 0; c < 16; ++c) cp[c] = (unsigned short)tjx[c];
    }
}

// ---------------- K2b: np-exact f32 rescore + rank + gather-mean, one WAVE per row ----------
__global__ __launch_bounds__(256) void k_rescore_agg(const float* __restrict__ x,
                                                     const float* __restrict__ xn,
                                                     const unsigned short* __restrict__ cand,
                                                     float* __restrict__ xagg) {
    __shared__ float s_sc[4][32];
    __shared__ int   s_ix[4][32];
    __shared__ int   s_win[4][8];
    int t  = threadIdx.x;
    int wv = t >> 6, l = t & 63;
    int nwg = ROWS / 4;                       // 24576
    int bid = blockIdx.x;
    int swz = (bid & 7) * (nwg >> 3) + (bid >> 3);
    size_t R = (size_t)swz * 4 + wv;          // global row
    int bj    = (int)(R >> 9);
    int i_loc = (int)(R & 511);
    const float* xnb = xn + (((size_t)bj) << 9) * D;
    const float* xb  = x  + (((size_t)bj) << 9) * D;

    int c   = l >> 1;
    int sub = l & 1;
    int jc  = (int)cand[R * 32 + c];
    const float* xi = xnb + (size_t)i_loc * D + 2 * sub;
    const float* xj = xnb + (size_t)jc * D + 2 * sub;
    float Pa = 0.f, Pb = 0.f;
    #pragma unroll
    for (int g = 0; g < 32; ++g) {
        float2 a2 = *(const float2*)(xi + g * 4);
        float2 b2 = *(const float2*)(xj + g * 4);
        Pa = __fadd_rn(Pa, __fmul_rn(a2.x, b2.x));
        Pb = __fadd_rn(Pb, __fmul_rn(a2.y, b2.y));
    }
    float s  = __fadd_rn(Pa, Pb);      // even: fadd(P0,P1); odd: fadd(P2,P3)
    float so = __shfl_xor(s, 1);
    if (sub == 0) {
        s_sc[wv][c] = __fadd_rn(s, so);   // fadd(fadd(P0,P1), fadd(P2,P3)) — exact order
        s_ix[wv][c] = jc;
    }
    __syncthreads();

    if (l < 32) {
        float v = s_sc[wv][l]; int iv = s_ix[wv][l];
        int rank = 0;
        #pragma unroll 1
        for (int o = 0; o < 32; ++o) {
            float vo = s_sc[wv][o]; int io = s_ix[wv][o];
            rank += ((vo > v) || (vo == v && io < iv)) ? 1 : 0;
        }
        if (rank < 8) s_win[wv][rank] = iv;
    }
    __syncthreads();

    {
        int iw[8];
        #pragma unroll
        for (int w8 = 0; w8 < 8; ++w8) iw[w8] = s_win[wv][w8];
        const float* bb = xb + 2 * l;
        float2 v[8];
        #pragma unroll
        for (int w8 = 0; w8 < 8; ++w8)
            v[w8] = *(const float2*)(bb + (size_t)iw[w8] * D);
        float2 a2;
        a2.x = __fadd_rn(__fadd_rn(__fadd_rn(v[0].x, v[1].x), __fadd_rn(v[2].x, v[3].x)),
                         __fadd_rn(__fadd_rn(v[4].x, v[5].x), __fadd_rn(v[6].x, v[7].x)));
        a2.y = __fadd_rn(__fadd_rn(__fadd_rn(v[0].y, v[1].y), __fadd_rn(v[2].y, v[3].y)),
                         __fadd_rn(__fadd_rn(v[4].y, v[5].y), __fadd_rn(v[6].y, v[7].y)));
        a2.x *= 0.125f; a2.y *= 0.125f;
        *(float2*)(xagg + R * D + 2 * l) = a2;
    }
}

// ---------------- K3: h = x_agg @ W + b, LayerNorm -> hn (in-place over x_agg ws) ----------------
// V3: __launch_bounds__(256,4) (LDS caps at 4 blk/CU anyway; raises VGPR cap 52->128) +
// W-stream prefetched one kc ahead into registers — kills the per-i vmcnt(0) stall chain.
// FMA accumulation order unchanged (bit-identical).
__global__ __launch_bounds__(256, 4) void k_gemm1_ln(float* __restrict__ ws0,
                                                  const float* __restrict__ W,
                                                  const float* __restrict__ bvec,
                                                  const float* __restrict__ gamma,
                                                  const float* __restrict__ beta) {
    __shared__ float s_a[64 * 132];
    __shared__ float s_red[640];
    int t = threadIdx.x;
    size_t row0 = (size_t)blockIdx.x * 64;

    #pragma unroll
    for (int r = 0; r < 8; ++r) {
        int id = t + 256 * r;
        int row = id >> 5, c4 = (id & 31) << 2;
        *(float4*)&s_a[row * 132 + c4] = *(const float4*)(ws0 + (row0 + row) * D + c4);
    }
    __syncthreads();

    int mg = t >> 4, ng = t & 15;
    float acc[4][8];
    #pragma unroll
    for (int s = 0; s < 4; ++s)
        #pragma unroll
        for (int n = 0; n < 8; ++n) acc[s][n] = 0.0f;

    const float* Wp = W + ng * 8;
    float4 bPA[4], bPB[4];
    #pragma unroll
    for (int i = 0; i < 4; ++i) {
        bPA[i] = *(const float4*)(Wp + i * D);
        bPB[i] = *(const float4*)(Wp + i * D + 4);
    }
    #pragma unroll 2
    for (int kc = 0; kc < 32; ++kc) {
        float4 a[4];
        #pragma unroll
        for (int s = 0; s < 4; ++s) a[s] = *(const float4*)&s_a[(mg + 16 * s) * 132 + kc * 4];
        float4 bCA[4], bCB[4];
        #pragma unroll
        for (int i = 0; i < 4; ++i) { bCA[i] = bPA[i]; bCB[i] = bPB[i]; }
        if (kc < 31) {
            #pragma unroll
            for (int i = 0; i < 4; ++i) {
                bPA[i] = *(const float4*)(Wp + (kc * 4 + 4 + i) * D);
                bPB[i] = *(const float4*)(Wp + (kc * 4 + 4 + i) * D + 4);
            }
        }
        #pragma unroll
        for (int i = 0; i < 4; ++i) {
            #pragma unroll
            for (int s = 0; s < 4; ++s) {
                float av = COMP(a[s], i);
                acc[s][0] = fmaf(av, bCA[i].x, acc[s][0]);
                acc[s][1] = fmaf(av, bCA[i].y, acc[s][1]);
                acc[s][2] = fmaf(av, bCA[i].z, acc[s][2]);
                acc[s][3] = fmaf(av, bCA[i].w, acc[s][3]);
                acc[s][4] = fmaf(av, bCB[i].x, acc[s][4]);
                acc[s][5] = fmaf(av, bCB[i].y, acc[s][5]);
                acc[s][6] = fmaf(av, bCB[i].z, acc[s][6]);
                acc[s][7] = fmaf(av, bCB[i].w, acc[s][7]);
            }
        }
    }
    __syncthreads();
    {
        float4 bA = *(const float4*)(bvec + ng * 8);
        float4 bB = *(const float4*)(bvec + ng * 8 + 4);
        #pragma unroll
        for (int s = 0; s < 4; ++s) {
            int row = mg + 16 * s;
            float4 h0 = make_float4(acc[s][0] + bA.x, acc[s][1] + bA.y,
                                    acc[s][2] + bA.z, acc[s][3] + bA.w);
            float4 h1 = make_float4(acc[s][4] + bB.x, acc[s][5] + bB.y,
                                    acc[s][6] + bB.z, acc[s][7] + bB.w);
            *(float4*)&s_a[row * 132 + ng * 8]     = h0;
            *(float4*)&s_a[row * 132 + ng * 8 + 4] = h1;
        }
    }
    __syncthreads();
    {
        int row = t & 63, q = t >> 6;
        float sm = 0.f, ssq = 0.f;
        #pragma unroll
        for (int c4 = 0; c4 < 8; ++c4) {
            float4 h = *(const float4*)&s_a[row * 132 + q * 32 + c4 * 4];
            sm += h.x + h.y + h.z + h.w;
            ssq = fmaf(h.x, h.x, ssq); ssq = fmaf(h.y, h.y, ssq);
            ssq = fmaf(h.z, h.z, ssq); ssq = fmaf(h.w, h.w, ssq);
        }
        s_red[row * 4 + q] = sm;
        s_red[256 + row * 4 + q] = ssq;
    }
    __syncthreads();
    if (t < 64) {
        float sm  = s_red[t * 4] + s_red[t * 4 + 1] + s_red[t * 4 + 2] + s_red[t * 4 + 3];
        float ssq = s_red[256 + t * 4] + s_red[256 + t * 4 + 1] +
                    s_red[256 + t * 4 + 2] + s_red[256 + t * 4 + 3];
        float mu  = sm * (1.0f / 128.0f);
        float var = ssq * (1.0f / 128.0f) - mu * mu;
        s_red[512 + t] = mu;
        s_red[576 + t] = 1.0f / sqrtf(var + 1e-5f);
    }
    __syncthreads();
    {
        int row = t & 63, q = t >> 6;
        float mu = s_red[512 + row], rs = s_red[576 + row];
        float* outp = ws0 + (row0 + row) * D + q * 32;
        #pragma unroll
        for (int c4 = 0; c4 < 8; ++c4) {
            float4 h  = *(const float4*)&s_a[row * 132 + q * 32 + c4 * 4];
            float4 g  = *(const float4*)(gamma + q * 32 + c4 * 4);
            float4 bt = *(const float4*)(beta  + q * 32 + c4 * 4);
            float4 o;
            o.x = fmaf((h.x - mu) * rs, g.x, bt.x);
            o.y = fmaf((h.y - mu) * rs, g.y, bt.y);
            o.z = fmaf((h.z - mu) * rs, g.z, bt.z);
            o.w = fmaf((h.w - mu) * rs, g.w, bt.w);
            *(float4*)(outp + c4 * 4) = o;
        }
    }
}

// ---------------- K4: out = relu(hn@W1+b1)@W2 + b2 ----------------
// V3: __launch_bounds__(256,4) + explicit one-kc-ahead register pipeline (aP/bP ping-pong
// via unroll 2). Was VGPR=52 -> per-i vmcnt(0) stall (VALUBusy 26%). FMA order unchanged.
__global__ __launch_bounds__(256, 4) void k_mlp(const float* __restrict__ hn,
                                             const float* __restrict__ W1,
                                             const float* __restrict__ b1,
                                             const float* __restrict__ W2,
                                             const float* __restrict__ b2,
                                             float* __restrict__ out) {
    __shared__ float s_h[32 * 132];
    __shared__ float s_t[32 * 132];
    int t = threadIdx.x;
    size_t row0 = (size_t)blockIdx.x * 32;

    #pragma unroll
    for (int r = 0; r < 4; ++r) {
        int id = t + 256 * r;
        int row = id >> 5, c4 = (id & 31) << 2;
        *(float4*)&s_h[row * 132 + c4] = *(const float4*)(hn + (row0 + row) * D + c4);
    }
    __syncthreads();

    int mg = t >> 5, ng = t & 31;
    float oacc[4][4];
    #pragma unroll
    for (int s = 0; s < 4; ++s)
        #pragma unroll
        for (int c = 0; c < 4; ++c) oacc[s][c] = 0.0f;

    for (int half = 0; half < 2; ++half) {
        float tacc[4][4];
        #pragma unroll
        for (int s = 0; s < 4; ++s)
            #pragma unroll
            for (int c = 0; c < 4; ++c) tacc[s][c] = 0.0f;
        // ---- GEMM1: tacc += s_h @ W1[:, half*128 + ng*4 ..] ----
        {
            const float* Wp = W1 + half * 128 + ng * 4;
            float4 aP[4], bP[4];
            #pragma unroll
            for (int s = 0; s < 4; ++s) aP[s] = *(const float4*)&s_h[(mg + 8 * s) * 132];
            #pragma unroll
            for (int i = 0; i < 4; ++i) bP[i] = *(const float4*)(Wp + i * 256);
            #pragma unroll 2
            for (int kc = 0; kc < 32; ++kc) {
                float4 aC[4], bC[4];
                #pragma unroll
                for (int s = 0; s < 4; ++s) aC[s] = aP[s];
                #pragma unroll
                for (int i = 0; i < 4; ++i) bC[i] = bP[i];
                if (kc < 31) {
                    #pragma unroll
                    for (int s = 0; s < 4; ++s)
                        aP[s] = *(const float4*)&s_h[(mg + 8 * s) * 132 + (kc + 1) * 4];
                    #pragma unroll
                    for (int i = 0; i < 4; ++i)
                        bP[i] = *(const float4*)(Wp + (kc * 4 + 4 + i) * 256);
                }
                #pragma unroll
                for (int i = 0; i < 4; ++i) {
                    #pragma unroll
                    for (int s = 0; s < 4; ++s) {
                        float av = COMP(aC[s], i);
                        tacc[s][0] = fmaf(av, bC[i].x, tacc[s][0]);
                        tacc[s][1] = fmaf(av, bC[i].y, tacc[s][1]);
                        tacc[s][2] = fmaf(av, bC[i].z, tacc[s][2]);
                        tacc[s][3] = fmaf(av, bC[i].w, tacc[s][3]);
                    }
                }
            }
        }
        float4 bb1 = *(const float4*)(b1 + half * 128 + ng * 4);
        #pragma unroll
        for (int s = 0; s < 4; ++s) {
            tacc[s][0] = fmaxf(tacc[s][0] + bb1.x, 0.0f);
            tacc[s][1] = fmaxf(tacc[s][1] + bb1.y, 0.0f);
            tacc[s][2] = fmaxf(tacc[s][2] + bb1.z, 0.0f);
            tacc[s][3] = fmaxf(tacc[s][3] + bb1.w, 0.0f);
        }
        __syncthreads();
        #pragma unroll
        for (int s = 0; s < 4; ++s)
            *(float4*)&s_t[(mg + 8 * s) * 132 + ng * 4] =
                make_float4(tacc[s][0], tacc[s][1], tacc[s][2], tacc[s][3]);
        __syncthreads();
        // ---- GEMM2: oacc += s_t @ W2[half*128.. , ng*4..] ----
        {
            const float* Wp = W2 + (size_t)(half * 128) * 128 + ng * 4;
            float4 aP[4], bP[4];
            #pragma unroll
            for (int s = 0; s < 4; ++s) aP[s] = *(const float4*)&s_t[(mg + 8 * s) * 132];
            #pragma unroll
            for (int i = 0; i < 4; ++i) bP[i] = *(const float4*)(Wp + i * 128);
            #pragma unroll 2
            for (int kc = 0; kc < 32; ++kc) {
                float4 aC[4], bC[4];
                #pragma unroll
                for (int s = 0; s < 4; ++s) aC[s] = aP[s];
                #pragma unroll
                for (int i = 0; i < 4; ++i) bC[i] = bP[i];
                if (kc < 31) {
                    #pragma unroll
                    for (int s = 0; s < 4; ++s)
                        aP[s] = *(const float4*)&s_t[(mg + 8 * s) * 132 + (kc + 1) * 4];
                    #pragma unroll
                    for (int i = 0; i < 4; ++i)
                        bP[i] = *(const float4*)(Wp + (kc * 4 + 4 + i) * 128);
                }
                #pragma unroll
                for (int i = 0; i < 4; ++i) {
                    #pragma unroll
                    for (int s = 0; s < 4; ++s) {
                        float av = COMP(aC[s], i);
                        oacc[s][0] = fmaf(av, bC[i].x, oacc[s][0]);
                        oacc[s][1] = fmaf(av, bC[i].y, oacc[s][1]);
                        oacc[s][2] = fmaf(av, bC[i].z, oacc[s][2]);
                        oacc[s][3] = fmaf(av, bC[i].w, oacc[s][3]);
                    }
                }
            }
        }
    }
    float4 bb2 = *(const float4*)(b2 + ng * 4);
    #pragma unroll
    for (int s = 0; s < 4; ++s) {
        float4 o = make_float4(oacc[s][0] + bb2.x, oacc[s][1] + bb2.y,
                               oacc[s][2] + bb2.z, oacc[s][3] + bb2.w);
        *(float4*)(out + (row0 + mg + 8 * s) * D + ng * 4) = o;
    }
}

extern "C" void kernel_launch(void* const* d_in, const int* in_sizes, int n_in,
                              void* d_out, int out_size, void* d_ws, size_t ws_size,
                              hipStream_t stream) {
    const float* x     = (const float*)d_in[0];
    const float* W     = (const float*)d_in[1];
    const float* b     = (const float*)d_in[2];
    const float* W1    = (const float*)d_in[3];
    const float* b1    = (const float*)d_in[4];
    const float* W2    = (const float*)d_in[5];
    const float* b2    = (const float*)d_in[6];
    const float* gamma = (const float*)d_in[7];
    const float* beta  = (const float*)d_in[8];

    float* ws   = (float*)d_ws;
    float* xagg = ws;                                   // ROWS*D f32; becomes hn after K3
    float* xn   = ws + (size_t)ROWS * D;                // ROWS*D f32 (np-bit-exact xn)
    unsigned short* xnbf = (unsigned short*)(ws + 2 * (size_t)ROWS * D);      // ROWS*D bf16
    unsigned short* cand = (unsigned short*)(ws + 2 * (size_t)ROWS * D + (size_t)ROWS * D / 2);
                                                        // ROWS*32 u16 candidate indices

    hipLaunchKernelGGL(k_normalize,   dim3(ROWS / 64), dim3(256), 0, stream, x, xn, xnbf);
    hipLaunchKernelGGL(k_topk_cand,   dim3(4, BJ),     dim3(256), 0, stream, xnbf, cand);
    hipLaunchKernelGGL(k_rescore_agg, dim3(ROWS / 4),  dim3(256), 0, stream, x, xn, cand, xagg);
    hipLaunchKernelGGL(k_gemm1_ln,    dim3(ROWS / 64), dim3(256), 0, stream, xagg, W, b, gamma, beta);
    hipLaunchKernelGGL(k_mlp,         dim3(ROWS / 32), dim3(256), 0, stream, xagg, W1, b1, W2, b2,
                       (float*)d_out);
}

// Round 4
// 955.140 us; speedup vs baseline: 1.3503x; 1.3503x over previous
//
#include <hip/hip_runtime.h>
#include <math.h>

#define BJ 192
#define L 512
#define D 128
#define ROWS (BJ*L)          // 98304
#define TI 128
#define TJ 64

#define COMP(v,i) ((i)==0?(v).x:((i)==1?(v).y:((i)==2?(v).z:(v).w)))

typedef __bf16 bf16x8 __attribute__((ext_vector_type(8)));
typedef float  f32x4  __attribute__((ext_vector_type(4)));

__device__ __forceinline__ unsigned short f2bf(float f) {
    unsigned int u = __float_as_uint(f);
    unsigned int r = (u + 0x7fffu + ((u >> 16) & 1u)) >> 16;   // RNE
    return (unsigned short)r;
}

// ---------------- K1: xn = x / max(norm(x),1e-12) (np-bit-exact) + bf16 copy ----------------
__global__ __launch_bounds__(256) void k_normalize(const float* __restrict__ x,
                                                   float* __restrict__ xn,
                                                   unsigned short* __restrict__ xnbf) {
    __shared__ float s_x[64 * 132];
    __shared__ float s_nrm[64];
    int t = threadIdx.x;
    size_t row0 = (size_t)blockIdx.x * 64;

    #pragma unroll
    for (int r = 0; r < 8; ++r) {
        int id = t + 256 * r;
        int row = id >> 5, c4 = (id & 31) << 2;
        *(float4*)&s_x[row * 132 + c4] = *(const float4*)(x + (row0 + row) * D + c4);
    }
    __syncthreads();
    if (t < 64) {
        int row = t;
        const float* p = &s_x[row * 132];
        float r8[8];
        #pragma unroll
        for (int l = 0; l < 8; ++l) r8[l] = 0.0f;
        #pragma unroll 1
        for (int i = 0; i < 16; ++i) {
            #pragma unroll
            for (int l = 0; l < 8; ++l) {
                float v = p[i * 8 + l];
                r8[l] = __fadd_rn(r8[l], __fmul_rn(v, v));
            }
        }
        float s01 = __fadd_rn(r8[0], r8[1]);
        float s23 = __fadd_rn(r8[2], r8[3]);
        float s45 = __fadd_rn(r8[4], r8[5]);
        float s67 = __fadd_rn(r8[6], r8[7]);
        float ss  = __fadd_rn(__fadd_rn(s01, s23), __fadd_rn(s45, s67));
        s_nrm[row] = fmaxf(__fsqrt_rn(ss), 1e-12f);
    }
    __syncthreads();
    {
        int row = t >> 2, seg = t & 3;
        float nrm = s_nrm[row];
        float* outp = xn + (row0 + row) * D + seg * 32;
        unsigned short* outb = xnbf + (row0 + row) * D + seg * 32;
        #pragma unroll
        for (int c = 0; c < 8; ++c) {
            float4 v = *(const float4*)&s_x[row * 132 + seg * 32 + c * 4];
            float4 o;
            o.x = __fdiv_rn(v.x, nrm);
            o.y = __fdiv_rn(v.y, nrm);
            o.z = __fdiv_rn(v.z, nrm);
            o.w = __fdiv_rn(v.w, nrm);
            *(float4*)(outp + c * 4) = o;
            ushort4 ob;
            ob.x = f2bf(o.x); ob.y = f2bf(o.y); ob.z = f2bf(o.z); ob.w = f2bf(o.w);
            *(ushort4*)(outb + c * 4) = ob;
        }
    }
}

// ---------------- K2a: bf16-MFMA candidate scores -> 32 candidate indices per row ------------
__global__ __launch_bounds__(256, 3) void k_topk_cand(const unsigned short* __restrict__ xnbf,
                                                      unsigned short* __restrict__ cand) {
    __shared__ __align__(16) char smem[34816];
    float* s_sc = (float*)smem;            // 128*68 floats, aliased over Xi/Bj staging

    int bj = blockIdx.y;
    int i0 = blockIdx.x * TI;
    int t  = threadIdx.x;
    int w  = t >> 6;            // wave 0..3
    int l  = t & 63;            // lane
    int quad = l >> 4;          // 0..3
    int m16  = l & 15;          // 0..15
    const unsigned short* xfb = xnbf + (size_t)bj * L * D;

    // ---- stage Xi (bf16, swizzled) ----
    #pragma unroll
    for (int r = 0; r < 8; ++r) {
        int id = t + 256 * r;
        int row = id >> 4, c = id & 15;
        uint4 v = *(const uint4*)(xfb + (size_t)(i0 + row) * D + c * 8);
        *(uint4*)(smem + row * 256 + ((c ^ (row & 15)) << 4)) = v;
    }
    __syncthreads();
    bf16x8 afr[2][4];
    #pragma unroll
    for (int mt = 0; mt < 2; ++mt)
        #pragma unroll
        for (int s = 0; s < 4; ++s) {
            int row = w * 32 + mt * 16 + m16;
            int c = s * 4 + quad;
            afr[mt][s] = *(const bf16x8*)(smem + row * 256 + ((c ^ m16) << 4));
        }
    __syncthreads();   // Xi region free

    float tv[16]; int tjx[16];
    #pragma unroll
    for (int c = 0; c < 16; ++c) { tv[c] = -3.4e38f; tjx[c] = 0; }

    for (int jt = 0; jt < L / TJ; ++jt) {   // 8 j-tiles of 64
        #pragma unroll
        for (int r = 0; r < 4; ++r) {
            int id = t + 256 * r;
            int row = id >> 4, c = id & 15;
            uint4 v = *(const uint4*)(xfb + (size_t)(jt * TJ + row) * D + c * 8);
            *(uint4*)(smem + row * 256 + ((c ^ (row & 15)) << 4)) = v;
        }
        __syncthreads();
        f32x4 acc[2][4];
        #pragma unroll
        for (int mt = 0; mt < 2; ++mt)
            #pragma unroll
            for (int u = 0; u < 4; ++u) acc[mt][u] = (f32x4){0.f, 0.f, 0.f, 0.f};
        #pragma unroll
        for (int s = 0; s < 4; ++s) {
            bf16x8 bfr[4];
            #pragma unroll
            for (int u = 0; u < 4; ++u) {
                int row = u * 16 + m16;
                int c = s * 4 + quad;
                bfr[u] = *(const bf16x8*)(smem + row * 256 + ((c ^ m16) << 4));
            }
            #pragma unroll
            for (int u = 0; u < 4; ++u)
                #pragma unroll
                for (int mt = 0; mt < 2; ++mt)
                    acc[mt][u] = __builtin_amdgcn_mfma_f32_16x16x32_bf16(
                        afr[mt][s], bfr[u], acc[mt][u], 0, 0, 0);
        }
        __syncthreads();   // Bj consumed; region now s_sc
        // C/D layout: col = lane&15, row = quad*4 + reg  [m89-verified]
        #pragma unroll
        for (int mt = 0; mt < 2; ++mt)
            #pragma unroll
            for (int u = 0; u < 4; ++u)
                #pragma unroll
                for (int reg = 0; reg < 4; ++reg) {
                    int irow = w * 32 + mt * 16 + quad * 4 + reg;
                    s_sc[irow * 68 + u * 16 + m16] = acc[mt][u][reg];
                }
        __syncthreads();
        // scan (pool semantics identical to R7: strict >, earlier j kept on ties)
        {
            int row = t & 127, q = t >> 7;
            const float* bp = &s_sc[row * 68 + q * 32];
            int jbase = jt * TJ + q * 32;
            float4 cur = *(const float4*)bp;
            #pragma unroll 1
            for (int s4 = 0; s4 < 8; ++s4) {
                float4 nxt = cur;
                if (s4 < 7) nxt = *(const float4*)(bp + (s4 + 1) * 4);
                float mx = fmaxf(fmaxf(cur.x, cur.y), fmaxf(cur.z, cur.w));
                if (mx > tv[15]) {
                    #pragma unroll
                    for (int e = 0; e < 4; ++e) {
                        float v = COMP(cur, e);
                        if (v > tv[15]) {
                            tv[15] = v; tjx[15] = jbase + s4 * 4 + e;
                            #pragma unroll
                            for (int p = 15; p > 0; --p) {
                                if (tv[p] > tv[p - 1]) {
                                    float ft = tv[p - 1]; tv[p - 1] = tv[p]; tv[p] = ft;
                                    int   it = tjx[p - 1]; tjx[p - 1] = tjx[p]; tjx[p] = it;
                                }
                            }
                        }
                    }
                }
                cur = nxt;
            }
        }
        __syncthreads();   // scan done before next stage overwrites
    }

    // dump candidates: row-global layout [R*32 + q*16 + c], j fits u16
    {
        int rowB = t & 127, qB = t >> 7;
        unsigned short* cp = cand + ((size_t)(bj * L + i0 + rowB)) * 32 + qB * 16;
        #pragma unroll
        for (int c = 0; c < 16; ++c) cp[c] = (unsigned short)tjx[c];
    }
}

// ---------------- K2b: np-exact f32 rescore + rank + gather-mean, one WAVE per row ----------
__global__ __launch_bounds__(256) void k_rescore_agg(const float* __restrict__ x,
                                                     const float* __restrict__ xn,
                                                     const unsigned short* __restrict__ cand,
                                                     float* __restrict__ xagg) {
    __shared__ float s_sc[4][32];
    __shared__ int   s_ix[4][32];
    __shared__ int   s_win[4][8];
    int t  = threadIdx.x;
    int wv = t >> 6, l = t & 63;
    int nwg = ROWS / 4;                       // 24576
    int bid = blockIdx.x;
    int swz = (bid & 7) * (nwg >> 3) + (bid >> 3);
    size_t R = (size_t)swz * 4 + wv;          // global row
    int bj    = (int)(R >> 9);
    int i_loc = (int)(R & 511);
    const float* xnb = xn + (((size_t)bj) << 9) * D;
    const float* xb  = x  + (((size_t)bj) << 9) * D;

    int c   = l >> 1;
    int sub = l & 1;
    int jc  = (int)cand[R * 32 + c];
    const float* xi = xnb + (size_t)i_loc * D + 2 * sub;
    const float* xj = xnb + (size_t)jc * D + 2 * sub;
    float Pa = 0.f, Pb = 0.f;
    #pragma unroll
    for (int g = 0; g < 32; ++g) {
        float2 a2 = *(const float2*)(xi + g * 4);
        float2 b2 = *(const float2*)(xj + g * 4);
        Pa = __fadd_rn(Pa, __fmul_rn(a2.x, b2.x));
        Pb = __fadd_rn(Pb, __fmul_rn(a2.y, b2.y));
    }
    float s  = __fadd_rn(Pa, Pb);      // even: fadd(P0,P1); odd: fadd(P2,P3)
    float so = __shfl_xor(s, 1);
    if (sub == 0) {
        s_sc[wv][c] = __fadd_rn(s, so);   // fadd(fadd(P0,P1), fadd(P2,P3)) — exact order
        s_ix[wv][c] = jc;
    }
    __syncthreads();

    if (l < 32) {
        float v = s_sc[wv][l]; int iv = s_ix[wv][l];
        int rank = 0;
        #pragma unroll 1
        for (int o = 0; o < 32; ++o) {
            float vo = s_sc[wv][o]; int io = s_ix[wv][o];
            rank += ((vo > v) || (vo == v && io < iv)) ? 1 : 0;
        }
        if (rank < 8) s_win[wv][rank] = iv;
    }
    __syncthreads();

    {
        int iw[8];
        #pragma unroll
        for (int w8 = 0; w8 < 8; ++w8) iw[w8] = s_win[wv][w8];
        const float* bb = xb + 2 * l;
        float2 v[8];
        #pragma unroll
        for (int w8 = 0; w8 < 8; ++w8)
            v[w8] = *(const float2*)(bb + (size_t)iw[w8] * D);
        float2 a2;
        a2.x = __fadd_rn(__fadd_rn(__fadd_rn(v[0].x, v[1].x), __fadd_rn(v[2].x, v[3].x)),
                         __fadd_rn(__fadd_rn(v[4].x, v[5].x), __fadd_rn(v[6].x, v[7].x)));
        a2.y = __fadd_rn(__fadd_rn(__fadd_rn(v[0].y, v[1].y), __fadd_rn(v[2].y, v[3].y)),
                         __fadd_rn(__fadd_rn(v[4].y, v[5].y), __fadd_rn(v[6].y, v[7].y)));
        a2.x *= 0.125f; a2.y *= 0.125f;
        *(float2*)(xagg + R * D + 2 * l) = a2;
    }
}

// ---------------- K34: fused  h=xagg@W+b -> LN -> relu(hn@W1+b1)@W2+b2 ----------------
// Inner loops contain ZERO global loads: each 16x128 f32 weight k-tile is staged through a
// single 8KB LDS buffer with T14 async-split (issue next-tile global->reg loads BEFORE the
// current tile's 256-FMA block; ds_write after the barrier). Register demand ~70 -> no
// spill possible (R3 post-mortem: launch_bounds hint + reg-prefetch => 64-VGPR collapse,
// 1.1GB scratch writes). All FP chains bit-identical to K3/K4: k-ascending fmaf per output,
// K3's verbatim LN partial/final expressions, K4's half-loop order.
__device__ __forceinline__ float4 ldw_tile(const float* __restrict__ base, int ldw,
                                           int kt, int id) {
    return *(const float4*)(base + (size_t)(kt * 16 + (id >> 5)) * ldw + (id & 31) * 4);
}

template<int LDW>
__device__ __forceinline__ void run_gemm(const float* __restrict__ a_lds,
                                         const float* __restrict__ wbase,
                                         float* __restrict__ s_w,
                                         float (&acc)[4][4],
                                         int t, int mg, int ng) {
    float4 sg0 = ldw_tile(wbase, LDW, 0, t);
    float4 sg1 = ldw_tile(wbase, LDW, 0, t + 256);
    *(float4*)&s_w[t * 4] = sg0;
    *(float4*)&s_w[(t + 256) * 4] = sg1;
    __syncthreads();
    #pragma unroll 1
    for (int kt = 0; kt < 8; ++kt) {
        if (kt < 7) {                       // issue next tile early (latency hides under FMAs)
            sg0 = ldw_tile(wbase, LDW, kt + 1, t);
            sg1 = ldw_tile(wbase, LDW, kt + 1, t + 256);
        }
        #pragma unroll
        for (int kc2 = 0; kc2 < 4; ++kc2) {
            float4 a[4];
            #pragma unroll
            for (int s = 0; s < 4; ++s)
                a[s] = *(const float4*)&a_lds[(mg + 8 * s) * 132 + kt * 16 + kc2 * 4];
            #pragma unroll
            for (int i = 0; i < 4; ++i) {
                float4 b = *(const float4*)&s_w[(kc2 * 4 + i) * 128 + ng * 4];
                #pragma unroll
                for (int s = 0; s < 4; ++s) {
                    float av = COMP(a[s], i);
                    acc[s][0] = fmaf(av, b.x, acc[s][0]);
                    acc[s][1] = fmaf(av, b.y, acc[s][1]);
                    acc[s][2] = fmaf(av, b.z, acc[s][2]);
                    acc[s][3] = fmaf(av, b.w, acc[s][3]);
                }
            }
        }
        __syncthreads();                    // all waves done reading s_w
        if (kt < 7) {
            *(float4*)&s_w[t * 4] = sg0;
            *(float4*)&s_w[(t + 256) * 4] = sg1;
            __syncthreads();                // tile ready
        }
    }
}

__global__ __launch_bounds__(256) void k_fused_mlp(const float* __restrict__ xagg,
                                                   const float* __restrict__ W,
                                                   const float* __restrict__ bvec,
                                                   const float* __restrict__ W1,
                                                   const float* __restrict__ b1,
                                                   const float* __restrict__ W2,
                                                   const float* __restrict__ b2,
                                                   const float* __restrict__ gamma,
                                                   const float* __restrict__ beta,
                                                   float* __restrict__ out) {
    __shared__ float s_h[32 * 132];    // xagg tile, later hn
    __shared__ float s_t[32 * 132];    // h (LN input), later relu-temp
    __shared__ float s_w[16 * 128];    // weight k-tile (single buffer, reg-staged)
    __shared__ float s_cb[768];        // 0:bvec 128:b1(256) 384:b2 512:gamma 640:beta
    __shared__ float s_red[320];       // LN partials + mu/rs
    int t = threadIdx.x;
    size_t row0 = (size_t)blockIdx.x * 32;
    int mg = t >> 5, ng = t & 31;

    // stage consts (once)
    if (t < 192) {
        float4 v;
        if (t < 32)       v = *(const float4*)(bvec  + t * 4);
        else if (t < 96)  v = *(const float4*)(b1    + (t - 32) * 4);
        else if (t < 128) v = *(const float4*)(b2    + (t - 96) * 4);
        else if (t < 160) v = *(const float4*)(gamma + (t - 128) * 4);
        else              v = *(const float4*)(beta  + (t - 160) * 4);
        *(float4*)&s_cb[t * 4] = v;
    }
    // stage xagg tile (padded 132)
    #pragma unroll
    for (int r = 0; r < 4; ++r) {
        int id = t + 256 * r;
        int row = id >> 5, c4 = (id & 31) << 2;
        *(float4*)&s_h[row * 132 + c4] = *(const float4*)(xagg + (row0 + row) * D + c4);
    }
    // (first barrier inside run_gemm covers s_h/s_cb staging)

    // ---- GEMM1: h = xagg @ W  (k-ascending fmaf chain == K3) ----
    float acc[4][4];
    #pragma unroll
    for (int s = 0; s < 4; ++s)
        #pragma unroll
        for (int c = 0; c < 4; ++c) acc[s][c] = 0.0f;
    run_gemm<128>(s_h, W, s_w, acc, t, mg, ng);

    // bias -> s_t (h)
    {
        float4 bb = *(const float4*)&s_cb[ng * 4];
        #pragma unroll
        for (int s = 0; s < 4; ++s) {
            float4 h = make_float4(acc[s][0] + bb.x, acc[s][1] + bb.y,
                                   acc[s][2] + bb.z, acc[s][3] + bb.w);
            *(float4*)&s_t[(mg + 8 * s) * 132 + ng * 4] = h;
        }
    }
    __syncthreads();

    // ---- LayerNorm (verbatim K3 arithmetic, 32-row tile) ----
    if (t < 128) {
        int row = t & 31, q = t >> 5;      // q 0..3, 32-col chunk
        float sm = 0.f, ssq = 0.f;
        #pragma unroll
        for (int c4 = 0; c4 < 8; ++c4) {
            float4 h = *(const float4*)&s_t[row * 132 + q * 32 + c4 * 4];
            sm += h.x + h.y + h.z + h.w;
            ssq = fmaf(h.x, h.x, ssq); ssq = fmaf(h.y, h.y, ssq);
            ssq = fmaf(h.z, h.z, ssq); ssq = fmaf(h.w, h.w, ssq);
        }
        s_red[row * 4 + q] = sm;
        s_red[128 + row * 4 + q] = ssq;
    }
    __syncthreads();
    if (t < 32) {
        float sm  = s_red[t * 4] + s_red[t * 4 + 1] + s_red[t * 4 + 2] + s_red[t * 4 + 3];
        float ssq = s_red[128 + t * 4] + s_red[128 + t * 4 + 1] +
                    s_red[128 + t * 4 + 2] + s_red[128 + t * 4 + 3];
        float mu  = sm * (1.0f / 128.0f);
        float var = ssq * (1.0f / 128.0f) - mu * mu;
        s_red[256 + t] = mu;
        s_red[288 + t] = 1.0f / sqrtf(var + 1e-5f);
    }
    __syncthreads();
    {   // normalize -> hn into s_h (elementwise; partition differs from K3, math identical)
        int row = t & 31, q8 = t >> 5;     // 8 chunks of 16 cols
        float mu = s_red[256 + row], rs = s_red[288 + row];
        #pragma unroll
        for (int c4 = 0; c4 < 4; ++c4) {
            int col = q8 * 16 + c4 * 4;
            float4 h  = *(const float4*)&s_t[row * 132 + col];
            float4 g  = *(const float4*)&s_cb[512 + col];
            float4 bt = *(const float4*)&s_cb[640 + col];
            float4 o;
            o.x = fmaf((h.x - mu) * rs, g.x, bt.x);
            o.y = fmaf((h.y - mu) * rs, g.y, bt.y);
            o.z = fmaf((h.z - mu) * rs, g.z, bt.z);
            o.w = fmaf((h.w - mu) * rs, g.w, bt.w);
            *(float4*)&s_h[row * 132 + col] = o;
        }
    }
    __syncthreads();

    // ---- MLP: out = relu(hn@W1+b1)@W2 + b2  (half-loop order == K4) ----
    float oacc[4][4];
    #pragma unroll
    for (int s = 0; s < 4; ++s)
        #pragma unroll
        for (int c = 0; c < 4; ++c) oacc[s][c] = 0.0f;

    #pragma unroll 1
    for (int half = 0; half < 2; ++half) {
        float tacc[4][4];
        #pragma unroll
        for (int s = 0; s < 4; ++s)
            #pragma unroll
            for (int c = 0; c < 4; ++c) tacc[s][c] = 0.0f;
        run_gemm<256>(s_h, W1 + half * 128, s_w, tacc, t, mg, ng);
        {
            float4 bb1 = *(const float4*)&s_cb[128 + half * 128 + ng * 4];
            #pragma unroll
            for (int s = 0; s < 4; ++s) {
                tacc[s][0] = fmaxf(tacc[s][0] + bb1.x, 0.0f);
                tacc[s][1] = fmaxf(tacc[s][1] + bb1.y, 0.0f);
                tacc[s][2] = fmaxf(tacc[s][2] + bb1.z, 0.0f);
                tacc[s][3] = fmaxf(tacc[s][3] + bb1.w, 0.0f);
            }
            #pragma unroll
            for (int s = 0; s < 4; ++s)
                *(float4*)&s_t[(mg + 8 * s) * 132 + ng * 4] =
                    make_float4(tacc[s][0], tacc[s][1], tacc[s][2], tacc[s][3]);
        }
        __syncthreads();   // s_t ready; s_w free (trailing bar of run_gemm + this one)
        run_gemm<128>(s_t, W2 + (size_t)(half * 128) * 128, s_w, oacc, t, mg, ng);
        __syncthreads();   // s_t free before next half overwrites
    }
    {
        float4 bb2 = *(const float4*)&s_cb[384 + ng * 4];
        #pragma unroll
        for (int s = 0; s < 4; ++s) {
            float4 o = make_float4(oacc[s][0] + bb2.x, oacc[s][1] + bb2.y,
                                   oacc[s][2] + bb2.z, oacc[s][3] + bb2.w);
            *(float4*)(out + (row0 + mg + 8 * s) * D + ng * 4) = o;
        }
    }
}

extern "C" void kernel_launch(void* const* d_in, const int* in_sizes, int n_in,
                              void* d_out, int out_size, void* d_ws, size_t ws_size,
                              hipStream_t stream) {
    const float* x     = (const float*)d_in[0];
    const float* W     = (const float*)d_in[1];
    const float* b     = (const float*)d_in[2];
    const float* W1    = (const float*)d_in[3];
    const float* b1    = (const float*)d_in[4];
    const float* W2    = (const float*)d_in[5];
    const float* b2    = (const float*)d_in[6];
    const float* gamma = (const float*)d_in[7];
    const float* beta  = (const float*)d_in[8];

    float* ws   = (float*)d_ws;
    float* xagg = ws;                                   // ROWS*D f32
    float* xn   = ws + (size_t)ROWS * D;                // ROWS*D f32 (np-bit-exact xn)
    unsigned short* xnbf = (unsigned short*)(ws + 2 * (size_t)ROWS * D);      // ROWS*D bf16
    unsigned short* cand = (unsigned short*)(ws + 2 * (size_t)ROWS * D + (size_t)ROWS * D / 2);
                                                        // ROWS*32 u16 candidate indices

    hipLaunchKernelGGL(k_normalize,   dim3(ROWS / 64), dim3(256), 0, stream, x, xn, xnbf);
    hipLaunchKernelGGL(k_topk_cand,   dim3(4, BJ),     dim3(256), 0, stream, xnbf, cand);
    hipLaunchKernelGGL(k_rescore_agg, dim3(ROWS / 4),  dim3(256), 0, stream, x, xn, cand, xagg);
    hipLaunchKernelGGL(k_fused_mlp,   dim3(ROWS / 32), dim3(256), 0, stream, xagg, W, b,
                       W1, b1, W2, b2, gamma, beta, (float*)d_out);
}

// Round 5
// 942.395 us; speedup vs baseline: 1.3686x; 1.0135x over previous
//
#include <hip/hip_runtime.h>
#include <math.h>

#define BJ 192
#define L 512
#define D 128
#define ROWS (BJ*L)          // 98304
#define TI 128
#define TJ 64

#define COMP(v,i) ((i)==0?(v).x:((i)==1?(v).y:((i)==2?(v).z:(v).w)))

typedef __bf16 bf16x8 __attribute__((ext_vector_type(8)));
typedef float  f32x4  __attribute__((ext_vector_type(4)));

__device__ __forceinline__ unsigned short f2bf(float f) {
    unsigned int u = __float_as_uint(f);
    unsigned int r = (u + 0x7fffu + ((u >> 16) & 1u)) >> 16;   // RNE
    return (unsigned short)r;
}

// ---------------- K1: xn = x / max(norm(x),1e-12) (np-bit-exact) + bf16 copy ----------------
__global__ __launch_bounds__(256) void k_normalize(const float* __restrict__ x,
                                                   float* __restrict__ xn,
                                                   unsigned short* __restrict__ xnbf) {
    __shared__ float s_x[64 * 132];
    __shared__ float s_nrm[64];
    int t = threadIdx.x;
    size_t row0 = (size_t)blockIdx.x * 64;

    #pragma unroll
    for (int r = 0; r < 8; ++r) {
        int id = t + 256 * r;
        int row = id >> 5, c4 = (id & 31) << 2;
        *(float4*)&s_x[row * 132 + c4] = *(const float4*)(x + (row0 + row) * D + c4);
    }
    __syncthreads();
    if (t < 64) {
        int row = t;
        const float* p = &s_x[row * 132];
        float r8[8];
        #pragma unroll
        for (int l = 0; l < 8; ++l) r8[l] = 0.0f;
        #pragma unroll 1
        for (int i = 0; i < 16; ++i) {
            #pragma unroll
            for (int l = 0; l < 8; ++l) {
                float v = p[i * 8 + l];
                r8[l] = __fadd_rn(r8[l], __fmul_rn(v, v));
            }
        }
        float s01 = __fadd_rn(r8[0], r8[1]);
        float s23 = __fadd_rn(r8[2], r8[3]);
        float s45 = __fadd_rn(r8[4], r8[5]);
        float s67 = __fadd_rn(r8[6], r8[7]);
        float ss  = __fadd_rn(__fadd_rn(s01, s23), __fadd_rn(s45, s67));
        s_nrm[row] = fmaxf(__fsqrt_rn(ss), 1e-12f);
    }
    __syncthreads();
    {
        int row = t >> 2, seg = t & 3;
        float nrm = s_nrm[row];
        float* outp = xn + (row0 + row) * D + seg * 32;
        unsigned short* outb = xnbf + (row0 + row) * D + seg * 32;
        #pragma unroll
        for (int c = 0; c < 8; ++c) {
            float4 v = *(const float4*)&s_x[row * 132 + seg * 32 + c * 4];
            float4 o;
            o.x = __fdiv_rn(v.x, nrm);
            o.y = __fdiv_rn(v.y, nrm);
            o.z = __fdiv_rn(v.z, nrm);
            o.w = __fdiv_rn(v.w, nrm);
            *(float4*)(outp + c * 4) = o;
            ushort4 ob;
            ob.x = f2bf(o.x); ob.y = f2bf(o.y); ob.z = f2bf(o.z); ob.w = f2bf(o.w);
            *(ushort4*)(outb + c * 4) = ob;
        }
    }
}

// ---------------- K2a: bf16-MFMA candidate scores -> 32 candidate indices per row ------------
// V5 (pure scheduling; scores/scan order/candidate set byte-identical to V4):
//  * De-aliased LDS: stg(16K, Bj tile) + s_sc(34K; Xi staged here, dies into afr regs).
//  * Software pipeline: issue Bj(t+1) global->reg loads BEFORE tile t's MFMA (latency
//    hides under 16 ds_read_b128 + 32 MFMA + writeback); ds_write after bar1.
//  * 2 barriers/jt (was 4); scan(t) overlaps next tile's frag-loads/MFMA across waves.
__global__ __launch_bounds__(256, 3) void k_topk_cand(const unsigned short* __restrict__ xnbf,
                                                      unsigned short* __restrict__ cand) {
    __shared__ __align__(16) char smem[16384 + 34816];
    char*  stg  = smem;                       // Bj tile staging (64 rows x 256 B)
    char*  xst  = smem + 16384;               // Xi staging (128 rows x 256 B), aliased on s_sc
    float* s_sc = (float*)(smem + 16384);     // 128*68 floats

    int bj = blockIdx.y;
    int i0 = blockIdx.x * TI;
    int t  = threadIdx.x;
    int w  = t >> 6;            // wave 0..3
    int l  = t & 63;            // lane
    int quad = l >> 4;          // 0..3
    int m16  = l & 15;          // 0..15
    const unsigned short* xfb = xnbf + (size_t)bj * L * D;

    // ---- stage Xi (bf16, swizzled) into xst ----
    #pragma unroll
    for (int r = 0; r < 8; ++r) {
        int id = t + 256 * r;
        int row = id >> 4, c = id & 15;
        uint4 v = *(const uint4*)(xfb + (size_t)(i0 + row) * D + c * 8);
        *(uint4*)(xst + row * 256 + ((c ^ (row & 15)) << 4)) = v;
    }
    __syncthreads();
    // ---- A-frags: wave w owns i-rows [w*32, w*32+32); register-resident for all jt ----
    bf16x8 afr[2][4];
    #pragma unroll
    for (int mt = 0; mt < 2; ++mt)
        #pragma unroll
        for (int s = 0; s < 4; ++s) {
            int row = w * 32 + mt * 16 + m16;
            int c = s * 4 + quad;
            afr[mt][s] = *(const bf16x8*)(xst + row * 256 + ((c ^ m16) << 4));
        }
    // ---- stage Bj(0) into stg (independent region; no barrier needed before) ----
    #pragma unroll
    for (int r = 0; r < 4; ++r) {
        int id = t + 256 * r;
        int row = id >> 4, c = id & 15;
        uint4 v = *(const uint4*)(xfb + (size_t)row * D + c * 8);
        *(uint4*)(stg + row * 256 + ((c ^ (row & 15)) << 4)) = v;
    }
    __syncthreads();   // afr reads drained (barrier waitcnt), Bj0 ready; xst region now free

    float tv[16]; int tjx[16];
    #pragma unroll
    for (int c = 0; c < 16; ++c) { tv[c] = -3.4e38f; tjx[c] = 0; }

    #pragma unroll 1
    for (int jt = 0; jt < L / TJ; ++jt) {   // 8 j-tiles of 64
        // ---- issue next Bj tile loads early (uniform branch; latency hides under MFMA) ----
        uint4 pf[4];
        if (jt < 7) {
            #pragma unroll
            for (int r = 0; r < 4; ++r) {
                int id = t + 256 * r;
                int row = id >> 4, c = id & 15;
                pf[r] = *(const uint4*)(xfb + (size_t)((jt + 1) * TJ + row) * D + c * 8);
            }
        }
        // ---- MFMA on current tile ----
        f32x4 acc[2][4];
        #pragma unroll
        for (int mt = 0; mt < 2; ++mt)
            #pragma unroll
            for (int u = 0; u < 4; ++u) acc[mt][u] = (f32x4){0.f, 0.f, 0.f, 0.f};
        #pragma unroll
        for (int s = 0; s < 4; ++s) {
            bf16x8 bfr[4];
            #pragma unroll
            for (int u = 0; u < 4; ++u) {
                int row = u * 16 + m16;
                int c = s * 4 + quad;
                bfr[u] = *(const bf16x8*)(stg + row * 256 + ((c ^ m16) << 4));
            }
            #pragma unroll
            for (int u = 0; u < 4; ++u)
                #pragma unroll
                for (int mt = 0; mt < 2; ++mt)
                    acc[mt][u] = __builtin_amdgcn_mfma_f32_16x16x32_bf16(
                        afr[mt][s], bfr[u], acc[mt][u], 0, 0, 0);
        }
        __syncthreads();   // bar1: stg consumed by all waves; prev scan done with s_sc
        // ---- writeback scores + write next Bj tile (independent LDS regions) ----
        // C/D layout: col = lane&15, row = quad*4 + reg  [m89-verified]
        #pragma unroll
        for (int mt = 0; mt < 2; ++mt)
            #pragma unroll
            for (int u = 0; u < 4; ++u)
                #pragma unroll
                for (int reg = 0; reg < 4; ++reg) {
                    int irow = w * 32 + mt * 16 + quad * 4 + reg;
                    s_sc[irow * 68 + u * 16 + m16] = acc[mt][u][reg];
                }
        if (jt < 7) {
            #pragma unroll
            for (int r = 0; r < 4; ++r) {
                int id = t + 256 * r;
                int row = id >> 4, c = id & 15;
                *(uint4*)(stg + row * 256 + ((c ^ (row & 15)) << 4)) = pf[r];
            }
        }
        __syncthreads();   // bar2: s_sc ready; stg(t+1) ready
        // ---- scan (pool semantics identical: strict >, ascending j, earlier j on ties) ----
        {
            int row = t & 127, q = t >> 7;
            const float* bp = &s_sc[row * 68 + q * 32];
            int jbase = jt * TJ + q * 32;
            float4 cur = *(const float4*)bp;
            #pragma unroll 1
            for (int s4 = 0; s4 < 8; ++s4) {
                float4 nxt = cur;
                if (s4 < 7) nxt = *(const float4*)(bp + (s4 + 1) * 4);
                float mx = fmaxf(fmaxf(cur.x, cur.y), fmaxf(cur.z, cur.w));
                if (mx > tv[15]) {
                    #pragma unroll
                    for (int e = 0; e < 4; ++e) {
                        float v = COMP(cur, e);
                        if (v > tv[15]) {
                            tv[15] = v; tjx[15] = jbase + s4 * 4 + e;
                            #pragma unroll
                            for (int p = 15; p > 0; --p) {
                                if (tv[p] > tv[p - 1]) {
                                    float ft = tv[p - 1]; tv[p - 1] = tv[p]; tv[p] = ft;
                                    int   it = tjx[p - 1]; tjx[p - 1] = tjx[p]; tjx[p] = it;
                                }
                            }
                        }
                    }
                }
                cur = nxt;
            }
        }
        // no barrier here: next iter's MFMA reads stg (ready); bar1 orders s_sc reuse
    }

    // dump candidates: row-global layout [R*32 + q*16 + c], j fits u16
    {
        int rowB = t & 127, qB = t >> 7;
        unsigned short* cp = cand + ((size_t)(bj * L + i0 + rowB)) * 32 + qB * 16;
        #pragma unroll
        for (int c = 0; c < 16; ++c) cp[c] = (unsigned short)tjx[c];
    }
}

// ---------------- K2b: np-exact f32 rescore + rank + gather-mean, one WAVE per row ----------
__global__ __launch_bounds__(256) void k_rescore_agg(const float* __restrict__ x,
                                                     const float* __restrict__ xn,
                                                     const unsigned short* __restrict__ cand,
                                                     float* __restrict__ xagg) {
    __shared__ float s_sc[4][32];
    __shared__ int   s_ix[4][32];
    __shared__ int   s_win[4][8];
    int t  = threadIdx.x;
    int wv = t >> 6, l = t & 63;
    int nwg = ROWS / 4;                       // 24576
    int bid = blockIdx.x;
    int swz = (bid & 7) * (nwg >> 3) + (bid >> 3);
    size_t R = (size_t)swz * 4 + wv;          // global row
    int bj    = (int)(R >> 9);
    int i_loc = (int)(R & 511);
    const float* xnb = xn + (((size_t)bj) << 9) * D;
    const float* xb  = x  + (((size_t)bj) << 9) * D;

    int c   = l >> 1;
    int sub = l & 1;
    int jc  = (int)cand[R * 32 + c];
    const float* xi = xnb + (size_t)i_loc * D + 2 * sub;
    const float* xj = xnb + (size_t)jc * D + 2 * sub;
    float Pa = 0.f, Pb = 0.f;
    #pragma unroll
    for (int g = 0; g < 32; ++g) {
        float2 a2 = *(const float2*)(xi + g * 4);
        float2 b2 = *(const float2*)(xj + g * 4);
        Pa = __fadd_rn(Pa, __fmul_rn(a2.x, b2.x));
        Pb = __fadd_rn(Pb, __fmul_rn(a2.y, b2.y));
    }
    float s  = __fadd_rn(Pa, Pb);      // even: fadd(P0,P1); odd: fadd(P2,P3)
    float so = __shfl_xor(s, 1);
    if (sub == 0) {
        s_sc[wv][c] = __fadd_rn(s, so);   // fadd(fadd(P0,P1), fadd(P2,P3)) — exact order
        s_ix[wv][c] = jc;
    }
    __syncthreads();

    if (l < 32) {
        float v = s_sc[wv][l]; int iv = s_ix[wv][l];
        int rank = 0;
        #pragma unroll 1
        for (int o = 0; o < 32; ++o) {
            float vo = s_sc[wv][o]; int io = s_ix[wv][o];
            rank += ((vo > v) || (vo == v && io < iv)) ? 1 : 0;
        }
        if (rank < 8) s_win[wv][rank] = iv;
    }
    __syncthreads();

    {
        int iw[8];
        #pragma unroll
        for (int w8 = 0; w8 < 8; ++w8) iw[w8] = s_win[wv][w8];
        const float* bb = xb + 2 * l;
        float2 v[8];
        #pragma unroll
        for (int w8 = 0; w8 < 8; ++w8)
            v[w8] = *(const float2*)(bb + (size_t)iw[w8] * D);
        float2 a2;
        a2.x = __fadd_rn(__fadd_rn(__fadd_rn(v[0].x, v[1].x), __fadd_rn(v[2].x, v[3].x)),
                         __fadd_rn(__fadd_rn(v[4].x, v[5].x), __fadd_rn(v[6].x, v[7].x)));
        a2.y = __fadd_rn(__fadd_rn(__fadd_rn(v[0].y, v[1].y), __fadd_rn(v[2].y, v[3].y)),
                         __fadd_rn(__fadd_rn(v[4].y, v[5].y), __fadd_rn(v[6].y, v[7].y)));
        a2.x *= 0.125f; a2.y *= 0.125f;
        *(float2*)(xagg + R * D + 2 * l) = a2;
    }
}

// ---------------- K34: fused  h=xagg@W+b -> LN -> relu(hn@W1+b1)@W2+b2 ----------------
__device__ __forceinline__ float4 ldw_tile(const float* __restrict__ base, int ldw,
                                           int kt, int id) {
    return *(const float4*)(base + (size_t)(kt * 16 + (id >> 5)) * ldw + (id & 31) * 4);
}

template<int LDW>
__device__ __forceinline__ void run_gemm(const float* __restrict__ a_lds,
                                         const float* __restrict__ wbase,
                                         float* __restrict__ s_w,
                                         float (&acc)[4][4],
                                         int t, int mg, int ng) {
    float4 sg0 = ldw_tile(wbase, LDW, 0, t);
    float4 sg1 = ldw_tile(wbase, LDW, 0, t + 256);
    *(float4*)&s_w[t * 4] = sg0;
    *(float4*)&s_w[(t + 256) * 4] = sg1;
    __syncthreads();
    #pragma unroll 1
    for (int kt = 0; kt < 8; ++kt) {
        if (kt < 7) {                       // issue next tile early (latency hides under FMAs)
            sg0 = ldw_tile(wbase, LDW, kt + 1, t);
            sg1 = ldw_tile(wbase, LDW, kt + 1, t + 256);
        }
        #pragma unroll
        for (int kc2 = 0; kc2 < 4; ++kc2) {
            float4 a[4];
            #pragma unroll
            for (int s = 0; s < 4; ++s)
                a[s] = *(const float4*)&a_lds[(mg + 8 * s) * 132 + kt * 16 + kc2 * 4];
            #pragma unroll
            for (int i = 0; i < 4; ++i) {
                float4 b = *(const float4*)&s_w[(kc2 * 4 + i) * 128 + ng * 4];
                #pragma unroll
                for (int s = 0; s < 4; ++s) {
                    float av = COMP(a[s], i);
                    acc[s][0] = fmaf(av, b.x, acc[s][0]);
                    acc[s][1] = fmaf(av, b.y, acc[s][1]);
                    acc[s][2] = fmaf(av, b.z, acc[s][2]);
                    acc[s][3] = fmaf(av, b.w, acc[s][3]);
                }
            }
        }
        __syncthreads();                    // all waves done reading s_w
        if (kt < 7) {
            *(float4*)&s_w[t * 4] = sg0;
            *(float4*)&s_w[(t + 256) * 4] = sg1;
            __syncthreads();                // tile ready
        }
    }
}

__global__ __launch_bounds__(256) void k_fused_mlp(const float* __restrict__ xagg,
                                                   const float* __restrict__ W,
                                                   const float* __restrict__ bvec,
                                                   const float* __restrict__ W1,
                                                   const float* __restrict__ b1,
                                                   const float* __restrict__ W2,
                                                   const float* __restrict__ b2,
                                                   const float* __restrict__ gamma,
                                                   const float* __restrict__ beta,
                                                   float* __restrict__ out) {
    __shared__ float s_h[32 * 132];    // xagg tile, later hn
    __shared__ float s_t[32 * 132];    // h (LN input), later relu-temp
    __shared__ float s_w[16 * 128];    // weight k-tile (single buffer, reg-staged)
    __shared__ float s_cb[768];        // 0:bvec 128:b1(256) 384:b2 512:gamma 640:beta
    __shared__ float s_red[320];       // LN partials + mu/rs
    int t = threadIdx.x;
    size_t row0 = (size_t)blockIdx.x * 32;
    int mg = t >> 5, ng = t & 31;

    // stage consts (once)
    if (t < 192) {
        float4 v;
        if (t < 32)       v = *(const float4*)(bvec  + t * 4);
        else if (t < 96)  v = *(const float4*)(b1    + (t - 32) * 4);
        else if (t < 128) v = *(const float4*)(b2    + (t - 96) * 4);
        else if (t < 160) v = *(const float4*)(gamma + (t - 128) * 4);
        else              v = *(const float4*)(beta  + (t - 160) * 4);
        *(float4*)&s_cb[t * 4] = v;
    }
    // stage xagg tile (padded 132)
    #pragma unroll
    for (int r = 0; r < 4; ++r) {
        int id = t + 256 * r;
        int row = id >> 5, c4 = (id & 31) << 2;
        *(float4*)&s_h[row * 132 + c4] = *(const float4*)(xagg + (row0 + row) * D + c4);
    }
    // (first barrier inside run_gemm covers s_h/s_cb staging)

    // ---- GEMM1: h = xagg @ W  (k-ascending fmaf chain == K3) ----
    float acc[4][4];
    #pragma unroll
    for (int s = 0; s < 4; ++s)
        #pragma unroll
        for (int c = 0; c < 4; ++c) acc[s][c] = 0.0f;
    run_gemm<128>(s_h, W, s_w, acc, t, mg, ng);

    // bias -> s_t (h)
    {
        float4 bb = *(const float4*)&s_cb[ng * 4];
        #pragma unroll
        for (int s = 0; s < 4; ++s) {
            float4 h = make_float4(acc[s][0] + bb.x, acc[s][1] + bb.y,
                                   acc[s][2] + bb.z, acc[s][3] + bb.w);
            *(float4*)&s_t[(mg + 8 * s) * 132 + ng * 4] = h;
        }
    }
    __syncthreads();

    // ---- LayerNorm (verbatim K3 arithmetic, 32-row tile) ----
    if (t < 128) {
        int row = t & 31, q = t >> 5;      // q 0..3, 32-col chunk
        float sm = 0.f, ssq = 0.f;
        #pragma unroll
        for (int c4 = 0; c4 < 8; ++c4) {
            float4 h = *(const float4*)&s_t[row * 132 + q * 32 + c4 * 4];
            sm += h.x + h.y + h.z + h.w;
            ssq = fmaf(h.x, h.x, ssq); ssq = fmaf(h.y, h.y, ssq);
            ssq = fmaf(h.z, h.z, ssq); ssq = fmaf(h.w, h.w, ssq);
        }
        s_red[row * 4 + q] = sm;
        s_red[128 + row * 4 + q] = ssq;
    }
    __syncthreads();
    if (t < 32) {
        float sm  = s_red[t * 4] + s_red[t * 4 + 1] + s_red[t * 4 + 2] + s_red[t * 4 + 3];
        float ssq = s_red[128 + t * 4] + s_red[128 + t * 4 + 1] +
                    s_red[128 + t * 4 + 2] + s_red[128 + t * 4 + 3];
        float mu  = sm * (1.0f / 128.0f);
        float var = ssq * (1.0f / 128.0f) - mu * mu;
        s_red[256 + t] = mu;
        s_red[288 + t] = 1.0f / sqrtf(var + 1e-5f);
    }
    __syncthreads();
    {   // normalize -> hn into s_h (elementwise; partition differs from K3, math identical)
        int row = t & 31, q8 = t >> 5;     // 8 chunks of 16 cols
        float mu = s_red[256 + row], rs = s_red[288 + row];
        #pragma unroll
        for (int c4 = 0; c4 < 4; ++c4) {
            int col = q8 * 16 + c4 * 4;
            float4 h  = *(const float4*)&s_t[row * 132 + col];
            float4 g  = *(const float4*)&s_cb[512 + col];
            float4 bt = *(const float4*)&s_cb[640 + col];
            float4 o;
            o.x = fmaf((h.x - mu) * rs, g.x, bt.x);
            o.y = fmaf((h.y - mu) * rs, g.y, bt.y);
            o.z = fmaf((h.z - mu) * rs, g.z, bt.z);
            o.w = fmaf((h.w - mu) * rs, g.w, bt.w);
            *(float4*)&s_h[row * 132 + col] = o;
        }
    }
    __syncthreads();

    // ---- MLP: out = relu(hn@W1+b1)@W2 + b2  (half-loop order == K4) ----
    float oacc[4][4];
    #pragma unroll
    for (int s = 0; s < 4; ++s)
        #pragma unroll
        for (int c = 0; c < 4; ++c) oacc[s][c] = 0.0f;

    #pragma unroll 1
    for (int half = 0; half < 2; ++half) {
        float tacc[4][4];
        #pragma unroll
        for (int s = 0; s < 4; ++s)
            #pragma unroll
            for (int c = 0; c < 4; ++c) tacc[s][c] = 0.0f;
        run_gemm<256>(s_h, W1 + half * 128, s_w, tacc, t, mg, ng);
        {
            float4 bb1 = *(const float4*)&s_cb[128 + half * 128 + ng * 4];
            #pragma unroll
            for (int s = 0; s < 4; ++s) {
                tacc[s][0] = fmaxf(tacc[s][0] + bb1.x, 0.0f);
                tacc[s][1] = fmaxf(tacc[s][1] + bb1.y, 0.0f);
                tacc[s][2] = fmaxf(tacc[s][2] + bb1.z, 0.0f);
                tacc[s][3] = fmaxf(tacc[s][3] + bb1.w, 0.0f);
            }
            #pragma unroll
            for (int s = 0; s < 4; ++s)
                *(float4*)&s_t[(mg + 8 * s) * 132 + ng * 4] =
                    make_float4(tacc[s][0], tacc[s][1], tacc[s][2], tacc[s][3]);
        }
        __syncthreads();   // s_t ready; s_w free (trailing bar of run_gemm + this one)
        run_gemm<128>(s_t, W2 + (size_t)(half * 128) * 128, s_w, oacc, t, mg, ng);
        __syncthreads();   // s_t free before next half overwrites
    }
    {
        float4 bb2 = *(const float4*)&s_cb[384 + ng * 4];
        #pragma unroll
        for (int s = 0; s < 4; ++s) {
            float4 o = make_float4(oacc[s][0] + bb2.x, oacc[s][1] + bb2.y,
                                   oacc[s][2] + bb2.z, oacc[s][3] + bb2.w);
            *(float4*)(out + (row0 + mg + 8 * s) * D + ng * 4) = o;
        }
    }
}

extern "C" void kernel_launch(void* const* d_in, const int* in_sizes, int n_in,
                              void* d_out, int out_size, void* d_ws, size_t ws_size,
                              hipStream_t stream) {
    const float* x     = (const float*)d_in[0];
    const float* W     = (const float*)d_in[1];
    const float* b     = (const float*)d_in[2];
    const float* W1    = (const float*)d_in[3];
    const float* b1    = (const float*)d_in[4];
    const float* W2    = (const float*)d_in[5];
    const float* b2    = (const float*)d_in[6];
    const float* gamma = (const float*)d_in[7];
    const float* beta  = (const float*)d_in[8];

    float* ws   = (float*)d_ws;
    float* xagg = ws;                                   // ROWS*D f32
    float* xn   = ws + (size_t)ROWS * D;                // ROWS*D f32 (np-bit-exact xn)
    unsigned short* xnbf = (unsigned short*)(ws + 2 * (size_t)ROWS * D);      // ROWS*D bf16
    unsigned short* cand = (unsigned short*)(ws + 2 * (size_t)ROWS * D + (size_t)ROWS * D / 2);
                                                        // ROWS*32 u16 candidate indices

    hipLaunchKernelGGL(k_normalize,   dim3(ROWS / 64), dim3(256), 0, stream, x, xn, xnbf);
    hipLaunchKernelGGL(k_topk_cand,   dim3(4, BJ),     dim3(256), 0, stream, xnbf, cand);
    hipLaunchKernelGGL(k_rescore_agg, dim3(ROWS / 4),  dim3(256), 0, stream, x, xn, cand, xagg);
    hipLaunchKernelGGL(k_fused_mlp,   dim3(ROWS / 32), dim3(256), 0, stream, xagg, W, b,
                       W1, b1, W2, b2, gamma, beta, (float*)d_out);
}

// Round 6
// 736.147 us; speedup vs baseline: 1.7520x; 1.2802x over previous
//
#include <hip/hip_runtime.h>
#include <math.h>

#define BJ 192
#define L 512
#define D 128
#define ROWS (BJ*L)          // 98304
#define TI 128
#define TJ 64

#define COMP(v,i) ((i)==0?(v).x:((i)==1?(v).y:((i)==2?(v).z:(v).w)))

typedef __bf16 bf16x8 __attribute__((ext_vector_type(8)));
typedef float  f32x4  __attribute__((ext_vector_type(4)));

__device__ __forceinline__ unsigned short f2bf(float f) {
    unsigned int u = __float_as_uint(f);
    unsigned int r = (u + 0x7fffu + ((u >> 16) & 1u)) >> 16;   // RNE
    return (unsigned short)r;
}

// ---------------- K1: xn = x / max(norm(x),1e-12) (np-bit-exact) + bf16 copy ----------------
__global__ __launch_bounds__(256) void k_normalize(const float* __restrict__ x,
                                                   float* __restrict__ xn,
                                                   unsigned short* __restrict__ xnbf) {
    __shared__ float s_x[64 * 132];
    __shared__ float s_nrm[64];
    int t = threadIdx.x;
    size_t row0 = (size_t)blockIdx.x * 64;

    #pragma unroll
    for (int r = 0; r < 8; ++r) {
        int id = t + 256 * r;
        int row = id >> 5, c4 = (id & 31) << 2;
        *(float4*)&s_x[row * 132 + c4] = *(const float4*)(x + (row0 + row) * D + c4);
    }
    __syncthreads();
    if (t < 64) {
        int row = t;
        const float* p = &s_x[row * 132];
        float r8[8];
        #pragma unroll
        for (int l = 0; l < 8; ++l) r8[l] = 0.0f;
        #pragma unroll 1
        for (int i = 0; i < 16; ++i) {
            #pragma unroll
            for (int l = 0; l < 8; ++l) {
                float v = p[i * 8 + l];
                r8[l] = __fadd_rn(r8[l], __fmul_rn(v, v));
            }
        }
        float s01 = __fadd_rn(r8[0], r8[1]);
        float s23 = __fadd_rn(r8[2], r8[3]);
        float s45 = __fadd_rn(r8[4], r8[5]);
        float s67 = __fadd_rn(r8[6], r8[7]);
        float ss  = __fadd_rn(__fadd_rn(s01, s23), __fadd_rn(s45, s67));
        s_nrm[row] = fmaxf(__fsqrt_rn(ss), 1e-12f);
    }
    __syncthreads();
    {
        int row = t >> 2, seg = t & 3;
        float nrm = s_nrm[row];
        float* outp = xn + (row0 + row) * D + seg * 32;
        unsigned short* outb = xnbf + (row0 + row) * D + seg * 32;
        #pragma unroll
        for (int c = 0; c < 8; ++c) {
            float4 v = *(const float4*)&s_x[row * 132 + seg * 32 + c * 4];
            float4 o;
            o.x = __fdiv_rn(v.x, nrm);
            o.y = __fdiv_rn(v.y, nrm);
            o.z = __fdiv_rn(v.z, nrm);
            o.w = __fdiv_rn(v.w, nrm);
            *(float4*)(outp + c * 4) = o;
            ushort4 ob;
            ob.x = f2bf(o.x); ob.y = f2bf(o.y); ob.z = f2bf(o.z); ob.w = f2bf(o.w);
            *(ushort4*)(outb + c * 4) = ob;
        }
    }
}

// ---------------- K2a: bf16-MFMA candidate scores -> 32 candidate indices per row ------------
// V6: selection rewritten as a DATA-INDEPENDENT sorting network (no divergent insertion
// chain — that serial dep chain was the 330us invariant across V4/V5).
// Semantics: pool = top-16 per (row,stripe) by total order (value desc, j asc). Encoded as
// unique u64 key (ord(v)<<32 | (511-j)); ord = monotone float->u32 with +-0 canonicalized
// (matches IEEE '>' + earlier-j-on-ties exactly). Per jt: 2x{sort16 asc (Batcher, 63 CE) ->
// elementwise-max vs desc pool (bitonic top-k trick) -> 4-stage bitonic desc cleanup}.
// Set-equality with the old insertion pool => bit-identical final output.
__device__ __forceinline__ unsigned long long mkkey(float v, int j) {
    unsigned int u = __float_as_uint(v);
    unsigned int m = (u & 0x80000000u) ? 0xFFFFFFFFu : 0x80000000u;
    unsigned int o = ((u & 0x7FFFFFFFu) == 0) ? 0x80000000u : (u ^ m);
    return ((unsigned long long)o << 32) | (unsigned int)(511 - j);
}
__device__ __forceinline__ void ceA(unsigned long long &a, unsigned long long &b) {
    if (a > b) { unsigned long long tt = a; a = b; b = tt; }   // ascending
}
__device__ __forceinline__ void ceD(unsigned long long &a, unsigned long long &b) {
    if (a < b) { unsigned long long tt = a; a = b; b = tt; }   // descending
}
__device__ __forceinline__ void sort16_asc(unsigned long long (&a)[16]) {
    #pragma unroll
    for (int p = 1; p < 16; p <<= 1)
        #pragma unroll
        for (int k = p; k >= 1; k >>= 1)
            #pragma unroll
            for (int j = k % p; j + k < 16; j += 2 * k)
                #pragma unroll
                for (int i = 0; i < k; ++i)
                    if (i + j + k < 16)
                        if ((i + j) / (2 * p) == (i + j + k) / (2 * p))
                            ceA(a[i + j], a[i + j + k]);
}
__device__ __forceinline__ void bimerge16_desc(unsigned long long (&a)[16]) {
    #pragma unroll
    for (int k = 8; k >= 1; k >>= 1)
        #pragma unroll
        for (int j = 0; j < 16; j += 2 * k)
            #pragma unroll
            for (int i = 0; i < k; ++i)
                ceD(a[j + i], a[j + i + k]);
}

__global__ __launch_bounds__(256, 3) void k_topk_cand(const unsigned short* __restrict__ xnbf,
                                                      unsigned short* __restrict__ cand) {
    __shared__ __align__(16) char smem[16384 + 34816];
    char*  stg  = smem;                       // Bj tile staging (64 rows x 256 B)
    char*  xst  = smem + 16384;               // Xi staging, aliased on s_sc
    float* s_sc = (float*)(smem + 16384);     // 128*68 floats

    int bj = blockIdx.y;
    int i0 = blockIdx.x * TI;
    int t  = threadIdx.x;
    int w  = t >> 6;            // wave 0..3
    int l  = t & 63;            // lane
    int quad = l >> 4;          // 0..3
    int m16  = l & 15;          // 0..15
    const unsigned short* xfb = xnbf + (size_t)bj * L * D;

    // ---- stage Xi (bf16, swizzled) into xst ----
    #pragma unroll
    for (int r = 0; r < 8; ++r) {
        int id = t + 256 * r;
        int row = id >> 4, c = id & 15;
        uint4 v = *(const uint4*)(xfb + (size_t)(i0 + row) * D + c * 8);
        *(uint4*)(xst + row * 256 + ((c ^ (row & 15)) << 4)) = v;
    }
    __syncthreads();
    // ---- A-frags: wave w owns i-rows [w*32, w*32+32); register-resident for all jt ----
    bf16x8 afr[2][4];
    #pragma unroll
    for (int mt = 0; mt < 2; ++mt)
        #pragma unroll
        for (int s = 0; s < 4; ++s) {
            int row = w * 32 + mt * 16 + m16;
            int c = s * 4 + quad;
            afr[mt][s] = *(const bf16x8*)(xst + row * 256 + ((c ^ m16) << 4));
        }
    // ---- stage Bj(0) into stg (independent region) ----
    #pragma unroll
    for (int r = 0; r < 4; ++r) {
        int id = t + 256 * r;
        int row = id >> 4, c = id & 15;
        uint4 v = *(const uint4*)(xfb + (size_t)row * D + c * 8);
        *(uint4*)(stg + row * 256 + ((c ^ (row & 15)) << 4)) = v;
    }

    unsigned long long P[16];                 // desc-sorted pool of u64 keys
    #pragma unroll
    for (int c = 0; c < 16; ++c) P[c] = 0ull; // sentinel: below any real key

    #pragma unroll 1
    for (int jt = 0; jt < L / TJ; ++jt) {   // 8 j-tiles of 64
        __syncthreads();   // bar1: stg(jt) staged by all waves; s_sc free (scan jt-1 done)
        // ---- MFMA on current tile ----
        f32x4 acc[2][4];
        #pragma unroll
        for (int mt = 0; mt < 2; ++mt)
            #pragma unroll
            for (int u = 0; u < 4; ++u) acc[mt][u] = (f32x4){0.f, 0.f, 0.f, 0.f};
        #pragma unroll
        for (int s = 0; s < 4; ++s) {
            bf16x8 bfr[4];
            #pragma unroll
            for (int u = 0; u < 4; ++u) {
                int row = u * 16 + m16;
                int c = s * 4 + quad;
                bfr[u] = *(const bf16x8*)(stg + row * 256 + ((c ^ m16) << 4));
            }
            #pragma unroll
            for (int u = 0; u < 4; ++u)
                #pragma unroll
                for (int mt = 0; mt < 2; ++mt)
                    acc[mt][u] = __builtin_amdgcn_mfma_f32_16x16x32_bf16(
                        afr[mt][s], bfr[u], acc[mt][u], 0, 0, 0);
        }
        // writeback scores (s_sc disjoint from stg; other waves may still read stg — ok)
        // C/D layout: col = lane&15, row = quad*4 + reg  [m89-verified]
        #pragma unroll
        for (int mt = 0; mt < 2; ++mt)
            #pragma unroll
            for (int u = 0; u < 4; ++u)
                #pragma unroll
                for (int reg = 0; reg < 4; ++reg) {
                    int irow = w * 32 + mt * 16 + quad * 4 + reg;
                    s_sc[irow * 68 + u * 16 + m16] = acc[mt][u][reg];
                }
        __syncthreads();   // bar2: s_sc ready; all waves done reading stg
        // ---- stage Bj(jt+1) (overwrites stg — safe after bar2; overlaps scans cross-wave) --
        if (jt < 7) {
            #pragma unroll
            for (int r = 0; r < 4; ++r) {
                int id = t + 256 * r;
                int row = id >> 4, c = id & 15;
                uint4 v = *(const uint4*)(xfb + (size_t)((jt + 1) * TJ + row) * D + c * 8);
                *(uint4*)(stg + row * 256 + ((c ^ (row & 15)) << 4)) = v;
            }
        }
        // ---- branchless top-16 update: 2 chunks of 16 ----
        {
            int row = t & 127, q = t >> 7;
            const float* bp = &s_sc[row * 68 + q * 32];
            int jb = jt * TJ + q * 32;
            #pragma unroll
            for (int h = 0; h < 2; ++h) {
                unsigned long long c16[16];
                #pragma unroll
                for (int f = 0; f < 4; ++f) {
                    float4 v4 = *(const float4*)(bp + h * 16 + f * 4);
                    int j0 = jb + h * 16 + f * 4;
                    c16[f * 4 + 0] = mkkey(v4.x, j0 + 0);
                    c16[f * 4 + 1] = mkkey(v4.y, j0 + 1);
                    c16[f * 4 + 2] = mkkey(v4.z, j0 + 2);
                    c16[f * 4 + 3] = mkkey(v4.w, j0 + 3);
                }
                sort16_asc(c16);
                // top-16 of (P desc) U (c16 asc): elementwise max = valley-bitonic
                #pragma unroll
                for (int i2 = 0; i2 < 16; ++i2)
                    P[i2] = P[i2] > c16[i2] ? P[i2] : c16[i2];
                bimerge16_desc(P);
            }
        }
        // no barrier: next bar1 orders s_sc reuse and stg readiness
    }

    // dump candidates: row-global layout [R*32 + q*16 + c] (order within 16 irrelevant)
    {
        int rowB = t & 127, qB = t >> 7;
        unsigned short* cp = cand + ((size_t)(bj * L + i0 + rowB)) * 32 + qB * 16;
        #pragma unroll
        for (int c = 0; c < 16; ++c)
            cp[c] = (unsigned short)(511 - (int)(P[c] & 0x1FFull));
    }
}

// ---------------- K2b: np-exact f32 rescore + rank + gather-mean, one WAVE per row ----------
__global__ __launch_bounds__(256) void k_rescore_agg(const float* __restrict__ x,
                                                     const float* __restrict__ xn,
                                                     const unsigned short* __restrict__ cand,
                                                     float* __restrict__ xagg) {
    __shared__ float s_sc[4][32];
    __shared__ int   s_ix[4][32];
    __shared__ int   s_win[4][8];
    int t  = threadIdx.x;
    int wv = t >> 6, l = t & 63;
    int nwg = ROWS / 4;                       // 24576
    int bid = blockIdx.x;
    int swz = (bid & 7) * (nwg >> 3) + (bid >> 3);
    size_t R = (size_t)swz * 4 + wv;          // global row
    int bj    = (int)(R >> 9);
    int i_loc = (int)(R & 511);
    const float* xnb = xn + (((size_t)bj) << 9) * D;
    const float* xb  = x  + (((size_t)bj) << 9) * D;

    int c   = l >> 1;
    int sub = l & 1;
    int jc  = (int)cand[R * 32 + c];
    const float* xi = xnb + (size_t)i_loc * D + 2 * sub;
    const float* xj = xnb + (size_t)jc * D + 2 * sub;
    float Pa = 0.f, Pb = 0.f;
    #pragma unroll
    for (int g = 0; g < 32; ++g) {
        float2 a2 = *(const float2*)(xi + g * 4);
        float2 b2 = *(const float2*)(xj + g * 4);
        Pa = __fadd_rn(Pa, __fmul_rn(a2.x, b2.x));
        Pb = __fadd_rn(Pb, __fmul_rn(a2.y, b2.y));
    }
    float s  = __fadd_rn(Pa, Pb);      // even: fadd(P0,P1); odd: fadd(P2,P3)
    float so = __shfl_xor(s, 1);
    if (sub == 0) {
        s_sc[wv][c] = __fadd_rn(s, so);   // fadd(fadd(P0,P1), fadd(P2,P3)) — exact order
        s_ix[wv][c] = jc;
    }
    __syncthreads();

    if (l < 32) {
        float v = s_sc[wv][l]; int iv = s_ix[wv][l];
        int rank = 0;
        #pragma unroll 1
        for (int o = 0; o < 32; ++o) {
            float vo = s_sc[wv][o]; int io = s_ix[wv][o];
            rank += ((vo > v) || (vo == v && io < iv)) ? 1 : 0;
        }
        if (rank < 8) s_win[wv][rank] = iv;
    }
    __syncthreads();

    {
        int iw[8];
        #pragma unroll
        for (int w8 = 0; w8 < 8; ++w8) iw[w8] = s_win[wv][w8];
        const float* bb = xb + 2 * l;
        float2 v[8];
        #pragma unroll
        for (int w8 = 0; w8 < 8; ++w8)
            v[w8] = *(const float2*)(bb + (size_t)iw[w8] * D);
        float2 a2;
        a2.x = __fadd_rn(__fadd_rn(__fadd_rn(v[0].x, v[1].x), __fadd_rn(v[2].x, v[3].x)),
                         __fadd_rn(__fadd_rn(v[4].x, v[5].x), __fadd_rn(v[6].x, v[7].x)));
        a2.y = __fadd_rn(__fadd_rn(__fadd_rn(v[0].y, v[1].y), __fadd_rn(v[2].y, v[3].y)),
                         __fadd_rn(__fadd_rn(v[4].y, v[5].y), __fadd_rn(v[6].y, v[7].y)));
        a2.x *= 0.125f; a2.y *= 0.125f;
        *(float2*)(xagg + R * D + 2 * l) = a2;
    }
}

// ---------------- K34: fused  h=xagg@W+b -> LN -> relu(hn@W1+b1)@W2+b2 ----------------
__device__ __forceinline__ float4 ldw_tile(const float* __restrict__ base, int ldw,
                                           int kt, int id) {
    return *(const float4*)(base + (size_t)(kt * 16 + (id >> 5)) * ldw + (id & 31) * 4);
}

template<int LDW>
__device__ __forceinline__ void run_gemm(const float* __restrict__ a_lds,
                                         const float* __restrict__ wbase,
                                         float* __restrict__ s_w,
                                         float (&acc)[4][4],
                                         int t, int mg, int ng) {
    float4 sg0 = ldw_tile(wbase, LDW, 0, t);
    float4 sg1 = ldw_tile(wbase, LDW, 0, t + 256);
    *(float4*)&s_w[t * 4] = sg0;
    *(float4*)&s_w[(t + 256) * 4] = sg1;
    __syncthreads();
    #pragma unroll 1
    for (int kt = 0; kt < 8; ++kt) {
        if (kt < 7) {                       // issue next tile early (latency hides under FMAs)
            sg0 = ldw_tile(wbase, LDW, kt + 1, t);
            sg1 = ldw_tile(wbase, LDW, kt + 1, t + 256);
        }
        #pragma unroll
        for (int kc2 = 0; kc2 < 4; ++kc2) {
            float4 a[4];
            #pragma unroll
            for (int s = 0; s < 4; ++s)
                a[s] = *(const float4*)&a_lds[(mg + 8 * s) * 132 + kt * 16 + kc2 * 4];
            #pragma unroll
            for (int i = 0; i < 4; ++i) {
                float4 b = *(const float4*)&s_w[(kc2 * 4 + i) * 128 + ng * 4];
                #pragma unroll
                for (int s = 0; s < 4; ++s) {
                    float av = COMP(a[s], i);
                    acc[s][0] = fmaf(av, b.x, acc[s][0]);
                    acc[s][1] = fmaf(av, b.y, acc[s][1]);
                    acc[s][2] = fmaf(av, b.z, acc[s][2]);
                    acc[s][3] = fmaf(av, b.w, acc[s][3]);
                }
            }
        }
        __syncthreads();                    // all waves done reading s_w
        if (kt < 7) {
            *(float4*)&s_w[t * 4] = sg0;
            *(float4*)&s_w[(t + 256) * 4] = sg1;
            __syncthreads();                // tile ready
        }
    }
}

__global__ __launch_bounds__(256) void k_fused_mlp(const float* __restrict__ xagg,
                                                   const float* __restrict__ W,
                                                   const float* __restrict__ bvec,
                                                   const float* __restrict__ W1,
                                                   const float* __restrict__ b1,
                                                   const float* __restrict__ W2,
                                                   const float* __restrict__ b2,
                                                   const float* __restrict__ gamma,
                                                   const float* __restrict__ beta,
                                                   float* __restrict__ out) {
    __shared__ float s_h[32 * 132];    // xagg tile, later hn
    __shared__ float s_t[32 * 132];    // h (LN input), later relu-temp
    __shared__ float s_w[16 * 128];    // weight k-tile (single buffer, reg-staged)
    __shared__ float s_cb[768];        // 0:bvec 128:b1(256) 384:b2 512:gamma 640:beta
    __shared__ float s_red[320];       // LN partials + mu/rs
    int t = threadIdx.x;
    size_t row0 = (size_t)blockIdx.x * 32;
    int mg = t >> 5, ng = t & 31;

    // stage consts (once)
    if (t < 192) {
        float4 v;
        if (t < 32)       v = *(const float4*)(bvec  + t * 4);
        else if (t < 96)  v = *(const float4*)(b1    + (t - 32) * 4);
        else if (t < 128) v = *(const float4*)(b2    + (t - 96) * 4);
        else if (t < 160) v = *(const float4*)(gamma + (t - 128) * 4);
        else              v = *(const float4*)(beta  + (t - 160) * 4);
        *(float4*)&s_cb[t * 4] = v;
    }
    // stage xagg tile (padded 132)
    #pragma unroll
    for (int r = 0; r < 4; ++r) {
        int id = t + 256 * r;
        int row = id >> 5, c4 = (id & 31) << 2;
        *(float4*)&s_h[row * 132 + c4] = *(const float4*)(xagg + (row0 + row) * D + c4);
    }
    // (first barrier inside run_gemm covers s_h/s_cb staging)

    // ---- GEMM1: h = xagg @ W  (k-ascending fmaf chain == K3) ----
    float acc[4][4];
    #pragma unroll
    for (int s = 0; s < 4; ++s)
        #pragma unroll
        for (int c = 0; c < 4; ++c) acc[s][c] = 0.0f;
    run_gemm<128>(s_h, W, s_w, acc, t, mg, ng);

    // bias -> s_t (h)
    {
        float4 bb = *(const float4*)&s_cb[ng * 4];
        #pragma unroll
        for (int s = 0; s < 4; ++s) {
            float4 h = make_float4(acc[s][0] + bb.x, acc[s][1] + bb.y,
                                   acc[s][2] + bb.z, acc[s][3] + bb.w);
            *(float4*)&s_t[(mg + 8 * s) * 132 + ng * 4] = h;
        }
    }
    __syncthreads();

    // ---- LayerNorm (verbatim K3 arithmetic, 32-row tile) ----
    if (t < 128) {
        int row = t & 31, q = t >> 5;      // q 0..3, 32-col chunk
        float sm = 0.f, ssq = 0.f;
        #pragma unroll
        for (int c4 = 0; c4 < 8; ++c4) {
            float4 h = *(const float4*)&s_t[row * 132 + q * 32 + c4 * 4];
            sm += h.x + h.y + h.z + h.w;
            ssq = fmaf(h.x, h.x, ssq); ssq = fmaf(h.y, h.y, ssq);
            ssq = fmaf(h.z, h.z, ssq); ssq = fmaf(h.w, h.w, ssq);
        }
        s_red[row * 4 + q] = sm;
        s_red[128 + row * 4 + q] = ssq;
    }
    __syncthreads();
    if (t < 32) {
        float sm  = s_red[t * 4] + s_red[t * 4 + 1] + s_red[t * 4 + 2] + s_red[t * 4 + 3];
        float ssq = s_red[128 + t * 4] + s_red[128 + t * 4 + 1] +
                    s_red[128 + t * 4 + 2] + s_red[128 + t * 4 + 3];
        float mu  = sm * (1.0f / 128.0f);
        float var = ssq * (1.0f / 128.0f) - mu * mu;
        s_red[256 + t] = mu;
        s_red[288 + t] = 1.0f / sqrtf(var + 1e-5f);
    }
    __syncthreads();
    {   // normalize -> hn into s_h (elementwise; partition differs from K3, math identical)
        int row = t & 31, q8 = t >> 5;     // 8 chunks of 16 cols
        float mu = s_red[256 + row], rs = s_red[288 + row];
        #pragma unroll
        for (int c4 = 0; c4 < 4; ++c4) {
            int col = q8 * 16 + c4 * 4;
            float4 h  = *(const float4*)&s_t[row * 132 + col];
            float4 g  = *(const float4*)&s_cb[512 + col];
            float4 bt = *(const float4*)&s_cb[640 + col];
            float4 o;
            o.x = fmaf((h.x - mu) * rs, g.x, bt.x);
            o.y = fmaf((h.y - mu) * rs, g.y, bt.y);
            o.z = fmaf((h.z - mu) * rs, g.z, bt.z);
            o.w = fmaf((h.w - mu) * rs, g.w, bt.w);
            *(float4*)&s_h[row * 132 + col] = o;
        }
    }
    __syncthreads();

    // ---- MLP: out = relu(hn@W1+b1)@W2 + b2  (half-loop order == K4) ----
    float oacc[4][4];
    #pragma unroll
    for (int s = 0; s < 4; ++s)
        #pragma unroll
        for (int c = 0; c < 4; ++c) oacc[s][c] = 0.0f;

    #pragma unroll 1
    for (int half = 0; half < 2; ++half) {
        float tacc[4][4];
        #pragma unroll
        for (int s = 0; s < 4; ++s)
            #pragma unroll
            for (int c = 0; c < 4; ++c) tacc[s][c] = 0.0f;
        run_gemm<256>(s_h, W1 + half * 128, s_w, tacc, t, mg, ng);
        {
            float4 bb1 = *(const float4*)&s_cb[128 + half * 128 + ng * 4];
            #pragma unroll
            for (int s = 0; s < 4; ++s) {
                tacc[s][0] = fmaxf(tacc[s][0] + bb1.x, 0.0f);
                tacc[s][1] = fmaxf(tacc[s][1] + bb1.y, 0.0f);
                tacc[s][2] = fmaxf(tacc[s][2] + bb1.z, 0.0f);
                tacc[s][3] = fmaxf(tacc[s][3] + bb1.w, 0.0f);
            }
            #pragma unroll
            for (int s = 0; s < 4; ++s)
                *(float4*)&s_t[(mg + 8 * s) * 132 + ng * 4] =
                    make_float4(tacc[s][0], tacc[s][1], tacc[s][2], tacc[s][3]);
        }
        __syncthreads();   // s_t ready; s_w free (trailing bar of run_gemm + this one)
        run_gemm<128>(s_t, W2 + (size_t)(half * 128) * 128, s_w, oacc, t, mg, ng);
        __syncthreads();   // s_t free before next half overwrites
    }
    {
        float4 bb2 = *(const float4*)&s_cb[384 + ng * 4];
        #pragma unroll
        for (int s = 0; s < 4; ++s) {
            float4 o = make_float4(oacc[s][0] + bb2.x, oacc[s][1] + bb2.y,
                                   oacc[s][2] + bb2.z, oacc[s][3] + bb2.w);
            *(float4*)(out + (row0 + mg + 8 * s) * D + ng * 4) = o;
        }
    }
}

extern "C" void kernel_launch(void* const* d_in, const int* in_sizes, int n_in,
                              void* d_out, int out_size, void* d_ws, size_t ws_size,
                              hipStream_t stream) {
    const float* x     = (const float*)d_in[0];
    const float* W     = (const float*)d_in[1];
    const float* b     = (const float*)d_in[2];
    const float* W1    = (const float*)d_in[3];
    const float* b1    = (const float*)d_in[4];
    const float* W2    = (const float*)d_in[5];
    const float* b2    = (const float*)d_in[6];
    const float* gamma = (const float*)d_in[7];
    const float* beta  = (const float*)d_in[8];

    float* ws   = (float*)d_ws;
    float* xagg = ws;                                   // ROWS*D f32
    float* xn   = ws + (size_t)ROWS * D;                // ROWS*D f32 (np-bit-exact xn)
    unsigned short* xnbf = (unsigned short*)(ws + 2 * (size_t)ROWS * D);      // ROWS*D bf16
    unsigned short* cand = (unsigned short*)(ws + 2 * (size_t)ROWS * D + (size_t)ROWS * D / 2);
                                                        // ROWS*32 u16 candidate indices

    hipLaunchKernelGGL(k_normalize,   dim3(ROWS / 64), dim3(256), 0, stream, x, xn, xnbf);
    hipLaunchKernelGGL(k_topk_cand,   dim3(4, BJ),     dim3(256), 0, stream, xnbf, cand);
    hipLaunchKernelGGL(k_rescore_agg, dim3(ROWS / 4),  dim3(256), 0, stream, x, xn, cand, xagg);
    hipLaunchKernelGGL(k_fused_mlp,   dim3(ROWS / 32), dim3(256), 0, stream, xagg, W, b,
                       W1, b1, W2, b2, gamma, beta, (float*)d_out);
}

// Round 7
// 731.366 us; speedup vs baseline: 1.7634x; 1.0065x over previous
//
#include <hip/hip_runtime.h>
#include <math.h>

#define BJ 192
#define L 512
#define D 128
#define ROWS (BJ*L)          // 98304
#define TI 128
#define TJ 64

#define COMP(v,i) ((i)==0?(v).x:((i)==1?(v).y:((i)==2?(v).z:(v).w)))

typedef __bf16 bf16x8 __attribute__((ext_vector_type(8)));
typedef float  f32x4  __attribute__((ext_vector_type(4)));

__device__ __forceinline__ unsigned short f2bf(float f) {
    unsigned int u = __float_as_uint(f);
    unsigned int r = (u + 0x7fffu + ((u >> 16) & 1u)) >> 16;   // RNE
    return (unsigned short)r;
}

// ---------------- K1: xn = x / max(norm(x),1e-12) (np-bit-exact) + bf16 copy ----------------
__global__ __launch_bounds__(256) void k_normalize(const float* __restrict__ x,
                                                   float* __restrict__ xn,
                                                   unsigned short* __restrict__ xnbf) {
    __shared__ float s_x[64 * 132];
    __shared__ float s_nrm[64];
    int t = threadIdx.x;
    size_t row0 = (size_t)blockIdx.x * 64;

    #pragma unroll
    for (int r = 0; r < 8; ++r) {
        int id = t + 256 * r;
        int row = id >> 5, c4 = (id & 31) << 2;
        *(float4*)&s_x[row * 132 + c4] = *(const float4*)(x + (row0 + row) * D + c4);
    }
    __syncthreads();
    if (t < 64) {
        int row = t;
        const float* p = &s_x[row * 132];
        float r8[8];
        #pragma unroll
        for (int l = 0; l < 8; ++l) r8[l] = 0.0f;
        #pragma unroll 1
        for (int i = 0; i < 16; ++i) {
            #pragma unroll
            for (int l = 0; l < 8; ++l) {
                float v = p[i * 8 + l];
                r8[l] = __fadd_rn(r8[l], __fmul_rn(v, v));
            }
        }
        float s01 = __fadd_rn(r8[0], r8[1]);
        float s23 = __fadd_rn(r8[2], r8[3]);
        float s45 = __fadd_rn(r8[4], r8[5]);
        float s67 = __fadd_rn(r8[6], r8[7]);
        float ss  = __fadd_rn(__fadd_rn(s01, s23), __fadd_rn(s45, s67));
        s_nrm[row] = fmaxf(__fsqrt_rn(ss), 1e-12f);
    }
    __syncthreads();
    {
        int row = t >> 2, seg = t & 3;
        float nrm = s_nrm[row];
        float* outp = xn + (row0 + row) * D + seg * 32;
        unsigned short* outb = xnbf + (row0 + row) * D + seg * 32;
        #pragma unroll
        for (int c = 0; c < 8; ++c) {
            float4 v = *(const float4*)&s_x[row * 132 + seg * 32 + c * 4];
            float4 o;
            o.x = __fdiv_rn(v.x, nrm);
            o.y = __fdiv_rn(v.y, nrm);
            o.z = __fdiv_rn(v.z, nrm);
            o.w = __fdiv_rn(v.w, nrm);
            *(float4*)(outp + c * 4) = o;
            ushort4 ob;
            ob.x = f2bf(o.x); ob.y = f2bf(o.y); ob.z = f2bf(o.z); ob.w = f2bf(o.w);
            *(ushort4*)(outb + c * 4) = ob;
        }
    }
}

// ---------------- K2a: bf16-MFMA candidate scores -> 32 candidate indices per row ------------
// V6 sorting-network selection (see R5 notes) — unchanged.
__device__ __forceinline__ unsigned long long mkkey(float v, int j) {
    unsigned int u = __float_as_uint(v);
    unsigned int m = (u & 0x80000000u) ? 0xFFFFFFFFu : 0x80000000u;
    unsigned int o = ((u & 0x7FFFFFFFu) == 0) ? 0x80000000u : (u ^ m);
    return ((unsigned long long)o << 32) | (unsigned int)(511 - j);
}
__device__ __forceinline__ void ceA(unsigned long long &a, unsigned long long &b) {
    if (a > b) { unsigned long long tt = a; a = b; b = tt; }   // ascending
}
__device__ __forceinline__ void ceD(unsigned long long &a, unsigned long long &b) {
    if (a < b) { unsigned long long tt = a; a = b; b = tt; }   // descending
}
__device__ __forceinline__ void sort16_asc(unsigned long long (&a)[16]) {
    #pragma unroll
    for (int p = 1; p < 16; p <<= 1)
        #pragma unroll
        for (int k = p; k >= 1; k >>= 1)
            #pragma unroll
            for (int j = k % p; j + k < 16; j += 2 * k)
                #pragma unroll
                for (int i = 0; i < k; ++i)
                    if (i + j + k < 16)
                        if ((i + j) / (2 * p) == (i + j + k) / (2 * p))
                            ceA(a[i + j], a[i + j + k]);
}
__device__ __forceinline__ void bimerge16_desc(unsigned long long (&a)[16]) {
    #pragma unroll
    for (int k = 8; k >= 1; k >>= 1)
        #pragma unroll
        for (int j = 0; j < 16; j += 2 * k)
            #pragma unroll
            for (int i = 0; i < k; ++i)
                ceD(a[j + i], a[j + i + k]);
}

__global__ __launch_bounds__(256, 3) void k_topk_cand(const unsigned short* __restrict__ xnbf,
                                                      unsigned short* __restrict__ cand) {
    __shared__ __align__(16) char smem[16384 + 34816];
    char*  stg  = smem;                       // Bj tile staging (64 rows x 256 B)
    char*  xst  = smem + 16384;               // Xi staging, aliased on s_sc
    float* s_sc = (float*)(smem + 16384);     // 128*68 floats

    int bj = blockIdx.y;
    int i0 = blockIdx.x * TI;
    int t  = threadIdx.x;
    int w  = t >> 6;            // wave 0..3
    int l  = t & 63;            // lane
    int quad = l >> 4;          // 0..3
    int m16  = l & 15;          // 0..15
    const unsigned short* xfb = xnbf + (size_t)bj * L * D;

    // ---- stage Xi (bf16, swizzled) into xst ----
    #pragma unroll
    for (int r = 0; r < 8; ++r) {
        int id = t + 256 * r;
        int row = id >> 4, c = id & 15;
        uint4 v = *(const uint4*)(xfb + (size_t)(i0 + row) * D + c * 8);
        *(uint4*)(xst + row * 256 + ((c ^ (row & 15)) << 4)) = v;
    }
    __syncthreads();
    // ---- A-frags: wave w owns i-rows [w*32, w*32+32); register-resident for all jt ----
    bf16x8 afr[2][4];
    #pragma unroll
    for (int mt = 0; mt < 2; ++mt)
        #pragma unroll
        for (int s = 0; s < 4; ++s) {
            int row = w * 32 + mt * 16 + m16;
            int c = s * 4 + quad;
            afr[mt][s] = *(const bf16x8*)(xst + row * 256 + ((c ^ m16) << 4));
        }
    // ---- stage Bj(0) into stg (independent region) ----
    #pragma unroll
    for (int r = 0; r < 4; ++r) {
        int id = t + 256 * r;
        int row = id >> 4, c = id & 15;
        uint4 v = *(const uint4*)(xfb + (size_t)row * D + c * 8);
        *(uint4*)(stg + row * 256 + ((c ^ (row & 15)) << 4)) = v;
    }

    unsigned long long P[16];                 // desc-sorted pool of u64 keys
    #pragma unroll
    for (int c = 0; c < 16; ++c) P[c] = 0ull; // sentinel: below any real key

    #pragma unroll 1
    for (int jt = 0; jt < L / TJ; ++jt) {   // 8 j-tiles of 64
        __syncthreads();   // bar1: stg(jt) staged by all waves; s_sc free (scan jt-1 done)
        // ---- MFMA on current tile ----
        f32x4 acc[2][4];
        #pragma unroll
        for (int mt = 0; mt < 2; ++mt)
            #pragma unroll
            for (int u = 0; u < 4; ++u) acc[mt][u] = (f32x4){0.f, 0.f, 0.f, 0.f};
        #pragma unroll
        for (int s = 0; s < 4; ++s) {
            bf16x8 bfr[4];
            #pragma unroll
            for (int u = 0; u < 4; ++u) {
                int row = u * 16 + m16;
                int c = s * 4 + quad;
                bfr[u] = *(const bf16x8*)(stg + row * 256 + ((c ^ m16) << 4));
            }
            #pragma unroll
            for (int u = 0; u < 4; ++u)
                #pragma unroll
                for (int mt = 0; mt < 2; ++mt)
                    acc[mt][u] = __builtin_amdgcn_mfma_f32_16x16x32_bf16(
                        afr[mt][s], bfr[u], acc[mt][u], 0, 0, 0);
        }
        // writeback scores (s_sc disjoint from stg; other waves may still read stg — ok)
        // C/D layout: col = lane&15, row = quad*4 + reg  [m89-verified]
        #pragma unroll
        for (int mt = 0; mt < 2; ++mt)
            #pragma unroll
            for (int u = 0; u < 4; ++u)
                #pragma unroll
                for (int reg = 0; reg < 4; ++reg) {
                    int irow = w * 32 + mt * 16 + quad * 4 + reg;
                    s_sc[irow * 68 + u * 16 + m16] = acc[mt][u][reg];
                }
        __syncthreads();   // bar2: s_sc ready; all waves done reading stg
        // ---- stage Bj(jt+1) (overwrites stg — safe after bar2; overlaps scans cross-wave) --
        if (jt < 7) {
            #pragma unroll
            for (int r = 0; r < 4; ++r) {
                int id = t + 256 * r;
                int row = id >> 4, c = id & 15;
                uint4 v = *(const uint4*)(xfb + (size_t)((jt + 1) * TJ + row) * D + c * 8);
                *(uint4*)(stg + row * 256 + ((c ^ (row & 15)) << 4)) = v;
            }
        }
        // ---- branchless top-16 update: 2 chunks of 16 ----
        {
            int row = t & 127, q = t >> 7;
            const float* bp = &s_sc[row * 68 + q * 32];
            int jb = jt * TJ + q * 32;
            #pragma unroll
            for (int h = 0; h < 2; ++h) {
                unsigned long long c16[16];
                #pragma unroll
                for (int f = 0; f < 4; ++f) {
                    float4 v4 = *(const float4*)(bp + h * 16 + f * 4);
                    int j0 = jb + h * 16 + f * 4;
                    c16[f * 4 + 0] = mkkey(v4.x, j0 + 0);
                    c16[f * 4 + 1] = mkkey(v4.y, j0 + 1);
                    c16[f * 4 + 2] = mkkey(v4.z, j0 + 2);
                    c16[f * 4 + 3] = mkkey(v4.w, j0 + 3);
                }
                sort16_asc(c16);
                // top-16 of (P desc) U (c16 asc): elementwise max = valley-bitonic
                #pragma unroll
                for (int i2 = 0; i2 < 16; ++i2)
                    P[i2] = P[i2] > c16[i2] ? P[i2] : c16[i2];
                bimerge16_desc(P);
            }
        }
        // no barrier: next bar1 orders s_sc reuse and stg readiness
    }

    // dump candidates: row-global layout [R*32 + q*16 + c] (order within 16 irrelevant)
    {
        int rowB = t & 127, qB = t >> 7;
        unsigned short* cp = cand + ((size_t)(bj * L + i0 + rowB)) * 32 + qB * 16;
        #pragma unroll
        for (int c = 0; c < 16; ++c)
            cp[c] = (unsigned short)(511 - (int)(P[c] & 0x1FFull));
    }
}

// ---------------- K2b: np-exact f32 rescore + rank + gather-mean, one WAVE per row ----------
// V7: (a) rescore = explicit 4-group batched prefetch (named cur/next regs force ~16 loads
// in flight; was VGPR=32 -> ~6 in flight -> 2000cy stall/wave). Chain order unchanged:
// groups ascending, Pa/Pb serial __fadd_rn, combine fadd(fadd(P0,P1),fadd(P2,P3)).
// (b) rank via u64 key + __shfl broadcasts (desc value, asc idx — mkkey total order,
// identical to old predicate); both pair-lanes compute tot symmetrically. No LDS score
// exchange, 1 barrier (was 2), LDS 1536->128 B.
__global__ __launch_bounds__(256) void k_rescore_agg(const float* __restrict__ x,
                                                     const float* __restrict__ xn,
                                                     const unsigned short* __restrict__ cand,
                                                     float* __restrict__ xagg) {
    __shared__ int s_win[4][8];
    int t  = threadIdx.x;
    int wv = t >> 6, l = t & 63;
    int nwg = ROWS / 4;                       // 24576
    int bid = blockIdx.x;
    int swz = (bid & 7) * (nwg >> 3) + (bid >> 3);
    size_t R = (size_t)swz * 4 + wv;          // global row
    int bj    = (int)(R >> 9);
    int i_loc = (int)(R & 511);
    const float* xnb = xn + (((size_t)bj) << 9) * D;
    const float* xb  = x  + (((size_t)bj) << 9) * D;

    // ---- rescore: candidate c = l>>1, sub-chain pair = l&1 ----
    int c   = l >> 1;
    int sub = l & 1;
    int jc  = (int)cand[R * 32 + c];
    const float* xi = xnb + (size_t)i_loc * D + 2 * sub;
    const float* xj = xnb + (size_t)jc * D + 2 * sub;

    float Pa = 0.f, Pb = 0.f;
    float2 A0 = *(const float2*)(xi + 0),  B0 = *(const float2*)(xj + 0);
    float2 A1 = *(const float2*)(xi + 4),  B1 = *(const float2*)(xj + 4);
    float2 A2 = *(const float2*)(xi + 8),  B2 = *(const float2*)(xj + 8);
    float2 A3 = *(const float2*)(xi + 12), B3 = *(const float2*)(xj + 12);
    #pragma unroll
    for (int b = 0; b < 8; ++b) {           // batch b = groups 4b..4b+3 (ascending)
        float2 nA0, nA1, nA2, nA3, nB0, nB1, nB2, nB3;
        if (b < 7) {                         // issue next batch before current compute
            const float* pi = xi + (b + 1) * 16;
            const float* pj = xj + (b + 1) * 16;
            nA0 = *(const float2*)(pi + 0);  nB0 = *(const float2*)(pj + 0);
            nA1 = *(const float2*)(pi + 4);  nB1 = *(const float2*)(pj + 4);
            nA2 = *(const float2*)(pi + 8);  nB2 = *(const float2*)(pj + 8);
            nA3 = *(const float2*)(pi + 12); nB3 = *(const float2*)(pj + 12);
        }
        Pa = __fadd_rn(Pa, __fmul_rn(A0.x, B0.x)); Pb = __fadd_rn(Pb, __fmul_rn(A0.y, B0.y));
        Pa = __fadd_rn(Pa, __fmul_rn(A1.x, B1.x)); Pb = __fadd_rn(Pb, __fmul_rn(A1.y, B1.y));
        Pa = __fadd_rn(Pa, __fmul_rn(A2.x, B2.x)); Pb = __fadd_rn(Pb, __fmul_rn(A2.y, B2.y));
        Pa = __fadd_rn(Pa, __fmul_rn(A3.x, B3.x)); Pb = __fadd_rn(Pb, __fmul_rn(A3.y, B3.y));
        if (b < 7) {
            A0 = nA0; A1 = nA1; A2 = nA2; A3 = nA3;
            B0 = nB0; B1 = nB1; B2 = nB2; B3 = nB3;
        }
    }
    float s  = __fadd_rn(Pa, Pb);             // even: fadd(P0,P1); odd: fadd(P2,P3)
    float so = __shfl_xor(s, 1);
    float tot = (sub == 0) ? __fadd_rn(s, so) : __fadd_rn(so, s);  // both: exact order

    // ---- rank among all 32 via key broadcasts (value desc, tie -> lower index) ----
    unsigned long long kk = mkkey(tot, jc);
    int rank = 0;
    #pragma unroll
    for (int o = 0; o < 32; ++o) {
        unsigned long long ko = __shfl(kk, o * 2);
        rank += (ko > kk) ? 1 : 0;
    }
    if (sub == 0 && rank < 8) s_win[wv][rank] = jc;
    __syncthreads();

    // ---- gather-mean of raw x rows; lane covers elems {2l, 2l+1} (coalesced/row) ----
    {
        int iw[8];
        #pragma unroll
        for (int w8 = 0; w8 < 8; ++w8) iw[w8] = s_win[wv][w8];
        const float* bb = xb + 2 * l;
        float2 v[8];
        #pragma unroll
        for (int w8 = 0; w8 < 8; ++w8)
            v[w8] = *(const float2*)(bb + (size_t)iw[w8] * D);
        float2 a2;
        a2.x = __fadd_rn(__fadd_rn(__fadd_rn(v[0].x, v[1].x), __fadd_rn(v[2].x, v[3].x)),
                         __fadd_rn(__fadd_rn(v[4].x, v[5].x), __fadd_rn(v[6].x, v[7].x)));
        a2.y = __fadd_rn(__fadd_rn(__fadd_rn(v[0].y, v[1].y), __fadd_rn(v[2].y, v[3].y)),
                         __fadd_rn(__fadd_rn(v[4].y, v[5].y), __fadd_rn(v[6].y, v[7].y)));
        a2.x *= 0.125f; a2.y *= 0.125f;
        *(float2*)(xagg + R * D + 2 * l) = a2;
    }
}

// ---------------- K34: fused  h=xagg@W+b -> LN -> relu(hn@W1+b1)@W2+b2 ----------------
__device__ __forceinline__ float4 ldw_tile(const float* __restrict__ base, int ldw,
                                           int kt, int id) {
    return *(const float4*)(base + (size_t)(kt * 16 + (id >> 5)) * ldw + (id & 31) * 4);
}

template<int LDW>
__device__ __forceinline__ void run_gemm(const float* __restrict__ a_lds,
                                         const float* __restrict__ wbase,
                                         float* __restrict__ s_w,
                                         float (&acc)[4][4],
                                         int t, int mg, int ng) {
    float4 sg0 = ldw_tile(wbase, LDW, 0, t);
    float4 sg1 = ldw_tile(wbase, LDW, 0, t + 256);
    *(float4*)&s_w[t * 4] = sg0;
    *(float4*)&s_w[(t + 256) * 4] = sg1;
    __syncthreads();
    #pragma unroll 1
    for (int kt = 0; kt < 8; ++kt) {
        if (kt < 7) {                       // issue next tile early (latency hides under FMAs)
            sg0 = ldw_tile(wbase, LDW, kt + 1, t);
            sg1 = ldw_tile(wbase, LDW, kt + 1, t + 256);
        }
        #pragma unroll
        for (int kc2 = 0; kc2 < 4; ++kc2) {
            float4 a[4];
            #pragma unroll
            for (int s = 0; s < 4; ++s)
                a[s] = *(const float4*)&a_lds[(mg + 8 * s) * 132 + kt * 16 + kc2 * 4];
            #pragma unroll
            for (int i = 0; i < 4; ++i) {
                float4 b = *(const float4*)&s_w[(kc2 * 4 + i) * 128 + ng * 4];
                #pragma unroll
                for (int s = 0; s < 4; ++s) {
                    float av = COMP(a[s], i);
                    acc[s][0] = fmaf(av, b.x, acc[s][0]);
                    acc[s][1] = fmaf(av, b.y, acc[s][1]);
                    acc[s][2] = fmaf(av, b.z, acc[s][2]);
                    acc[s][3] = fmaf(av, b.w, acc[s][3]);
                }
            }
        }
        __syncthreads();                    // all waves done reading s_w
        if (kt < 7) {
            *(float4*)&s_w[t * 4] = sg0;
            *(float4*)&s_w[(t + 256) * 4] = sg1;
            __syncthreads();                // tile ready
        }
    }
}

__global__ __launch_bounds__(256) void k_fused_mlp(const float* __restrict__ xagg,
                                                   const float* __restrict__ W,
                                                   const float* __restrict__ bvec,
                                                   const float* __restrict__ W1,
                                                   const float* __restrict__ b1,
                                                   const float* __restrict__ W2,
                                                   const float* __restrict__ b2,
                                                   const float* __restrict__ gamma,
                                                   const float* __restrict__ beta,
                                                   float* __restrict__ out) {
    __shared__ float s_h[32 * 132];    // xagg tile, later hn
    __shared__ float s_t[32 * 132];    // h (LN input), later relu-temp
    __shared__ float s_w[16 * 128];    // weight k-tile (single buffer, reg-staged)
    __shared__ float s_cb[768];        // 0:bvec 128:b1(256) 384:b2 512:gamma 640:beta
    __shared__ float s_red[320];       // LN partials + mu/rs
    int t = threadIdx.x;
    size_t row0 = (size_t)blockIdx.x * 32;
    int mg = t >> 5, ng = t & 31;

    // stage consts (once)
    if (t < 192) {
        float4 v;
        if (t < 32)       v = *(const float4*)(bvec  + t * 4);
        else if (t < 96)  v = *(const float4*)(b1    + (t - 32) * 4);
        else if (t < 128) v = *(const float4*)(b2    + (t - 96) * 4);
        else if (t < 160) v = *(const float4*)(gamma + (t - 128) * 4);
        else              v = *(const float4*)(beta  + (t - 160) * 4);
        *(float4*)&s_cb[t * 4] = v;
    }
    // stage xagg tile (padded 132)
    #pragma unroll
    for (int r = 0; r < 4; ++r) {
        int id = t + 256 * r;
        int row = id >> 5, c4 = (id & 31) << 2;
        *(float4*)&s_h[row * 132 + c4] = *(const float4*)(xagg + (row0 + row) * D + c4);
    }
    // (first barrier inside run_gemm covers s_h/s_cb staging)

    // ---- GEMM1: h = xagg @ W  (k-ascending fmaf chain == K3) ----
    float acc[4][4];
    #pragma unroll
    for (int s = 0; s < 4; ++s)
        #pragma unroll
        for (int c = 0; c < 4; ++c) acc[s][c] = 0.0f;
    run_gemm<128>(s_h, W, s_w, acc, t, mg, ng);

    // bias -> s_t (h)
    {
        float4 bb = *(const float4*)&s_cb[ng * 4];
        #pragma unroll
        for (int s = 0; s < 4; ++s) {
            float4 h = make_float4(acc[s][0] + bb.x, acc[s][1] + bb.y,
                                   acc[s][2] + bb.z, acc[s][3] + bb.w);
            *(float4*)&s_t[(mg + 8 * s) * 132 + ng * 4] = h;
        }
    }
    __syncthreads();

    // ---- LayerNorm (verbatim K3 arithmetic, 32-row tile) ----
    if (t < 128) {
        int row = t & 31, q = t >> 5;      // q 0..3, 32-col chunk
        float sm = 0.f, ssq = 0.f;
        #pragma unroll
        for (int c4 = 0; c4 < 8; ++c4) {
            float4 h = *(const float4*)&s_t[row * 132 + q * 32 + c4 * 4];
            sm += h.x + h.y + h.z + h.w;
            ssq = fmaf(h.x, h.x, ssq); ssq = fmaf(h.y, h.y, ssq);
            ssq = fmaf(h.z, h.z, ssq); ssq = fmaf(h.w, h.w, ssq);
        }
        s_red[row * 4 + q] = sm;
        s_red[128 + row * 4 + q] = ssq;
    }
    __syncthreads();
    if (t < 32) {
        float sm  = s_red[t * 4] + s_red[t * 4 + 1] + s_red[t * 4 + 2] + s_red[t * 4 + 3];
        float ssq = s_red[128 + t * 4] + s_red[128 + t * 4 + 1] +
                    s_red[128 + t * 4 + 2] + s_red[128 + t * 4 + 3];
        float mu  = sm * (1.0f / 128.0f);
        float var = ssq * (1.0f / 128.0f) - mu * mu;
        s_red[256 + t] = mu;
        s_red[288 + t] = 1.0f / sqrtf(var + 1e-5f);
    }
    __syncthreads();
    {   // normalize -> hn into s_h (elementwise; partition differs from K3, math identical)
        int row = t & 31, q8 = t >> 5;     // 8 chunks of 16 cols
        float mu = s_red[256 + row], rs = s_red[288 + row];
        #pragma unroll
        for (int c4 = 0; c4 < 4; ++c4) {
            int col = q8 * 16 + c4 * 4;
            float4 h  = *(const float4*)&s_t[row * 132 + col];
            float4 g  = *(const float4*)&s_cb[512 + col];
            float4 bt = *(const float4*)&s_cb[640 + col];
            float4 o;
            o.x = fmaf((h.x - mu) * rs, g.x, bt.x);
            o.y = fmaf((h.y - mu) * rs, g.y, bt.y);
            o.z = fmaf((h.z - mu) * rs, g.z, bt.z);
            o.w = fmaf((h.w - mu) * rs, g.w, bt.w);
            *(float4*)&s_h[row * 132 + col] = o;
        }
    }
    __syncthreads();

    // ---- MLP: out = relu(hn@W1+b1)@W2 + b2  (half-loop order == K4) ----
    float oacc[4][4];
    #pragma unroll
    for (int s = 0; s < 4; ++s)
        #pragma unroll
        for (int c = 0; c < 4; ++c) oacc[s][c] = 0.0f;

    #pragma unroll 1
    for (int half = 0; half < 2; ++half) {
        float tacc[4][4];
        #pragma unroll
        for (int s = 0; s < 4; ++s)
            #pragma unroll
            for (int c = 0; c < 4; ++c) tacc[s][c] = 0.0f;
        run_gemm<256>(s_h, W1 + half * 128, s_w, tacc, t, mg, ng);
        {
            float4 bb1 = *(const float4*)&s_cb[128 + half * 128 + ng * 4];
            #pragma unroll
            for (int s = 0; s < 4; ++s) {
                tacc[s][0] = fmaxf(tacc[s][0] + bb1.x, 0.0f);
                tacc[s][1] = fmaxf(tacc[s][1] + bb1.y, 0.0f);
                tacc[s][2] = fmaxf(tacc[s][2] + bb1.z, 0.0f);
                tacc[s][3] = fmaxf(tacc[s][3] + bb1.w, 0.0f);
            }
            #pragma unroll
            for (int s = 0; s < 4; ++s)
                *(float4*)&s_t[(mg + 8 * s) * 132 + ng * 4] =
                    make_float4(tacc[s][0], tacc[s][1], tacc[s][2], tacc[s][3]);
        }
        __syncthreads();   // s_t ready; s_w free (trailing bar of run_gemm + this one)
        run_gemm<128>(s_t, W2 + (size_t)(half * 128) * 128, s_w, oacc, t, mg, ng);
        __syncthreads();   // s_t free before next half overwrites
    }
    {
        float4 bb2 = *(const float4*)&s_cb[384 + ng * 4];
        #pragma unroll
        for (int s = 0; s < 4; ++s) {
            float4 o = make_float4(oacc[s][0] + bb2.x, oacc[s][1] + bb2.y,
                                   oacc[s][2] + bb2.z, oacc[s][3] + bb2.w);
            *(float4*)(out + (row0 + mg + 8 * s) * D + ng * 4) = o;
        }
    }
}

extern "C" void kernel_launch(void* const* d_in, const int* in_sizes, int n_in,
                              void* d_out, int out_size, void* d_ws, size_t ws_size,
                              hipStream_t stream) {
    const float* x     = (const float*)d_in[0];
    const float* W     = (const float*)d_in[1];
    const float* b     = (const float*)d_in[2];
    const float* W1    = (const float*)d_in[3];
    const float* b1    = (const float*)d_in[4];
    const float* W2    = (const float*)d_in[5];
    const float* b2    = (const float*)d_in[6];
    const float* gamma = (const float*)d_in[7];
    const float* beta  = (const float*)d_in[8];

    float* ws   = (float*)d_ws;
    float* xagg = ws;                                   // ROWS*D f32
    float* xn   = ws + (size_t)ROWS * D;                // ROWS*D f32 (np-bit-exact xn)
    unsigned short* xnbf = (unsigned short*)(ws + 2 * (size_t)ROWS * D);      // ROWS*D bf16
    unsigned short* cand = (unsigned short*)(ws + 2 * (size_t)ROWS * D + (size_t)ROWS * D / 2);
                                                        // ROWS*32 u16 candidate indices

    hipLaunchKernelGGL(k_normalize,   dim3(ROWS / 64), dim3(256), 0, stream, x, xn, xnbf);
    hipLaunchKernelGGL(k_topk_cand,   dim3(4, BJ),     dim3(256), 0, stream, xnbf, cand);
    hipLaunchKernelGGL(k_rescore_agg, dim3(ROWS / 4),  dim3(256), 0, stream, x, xn, cand, xagg);
    hipLaunchKernelGGL(k_fused_mlp,   dim3(ROWS / 32), dim3(256), 0, stream, xagg, W, b,
                       W1, b1, W2, b2, gamma, beta, (float*)d_out);
}